// Round 1
// baseline (268.694 us; speedup 1.0000x reference)
//
#include <hip/hip_runtime.h>

#define PI_F 3.14159265358979323846f

struct C2 { float x, y; };
__device__ __forceinline__ C2 cmul(C2 a, C2 b) {
    return C2{a.x * b.x - a.y * b.y, a.x * b.y + a.y * b.x};
}

// Apply 2x2 (possibly complex) gate M on wire w to the statevector held one
// amplitude per lane (lane l = basis index, bit of wire w is bit (3-w) of l).
__device__ __forceinline__ void gate1(float& re, float& im, int l, int w,
                                      C2 m00, C2 m01, C2 m10, C2 m11) {
    int mask = 1 << (3 - w);
    float pre = __shfl_xor(re, mask, 64);
    float pim = __shfl_xor(im, mask, 64);
    bool b = (l & mask) != 0;
    C2 d = b ? m11 : m00;
    C2 o = b ? m10 : m01;
    float nre = d.x * re - d.y * im + o.x * pre - o.y * pim;
    float nim = d.x * im + d.y * re + o.x * pim + o.y * pre;
    re = nre; im = nim;
}

__global__ __launch_bounds__(256) void qnn_fused(
    const float* __restrict__ xg,
    const float* __restrict__ w1g, const float* __restrict__ b1g,
    const float* __restrict__ w2g, const float* __restrict__ b2g,
    const float* __restrict__ dwg, const float* __restrict__ dbg,
    const float* __restrict__ qpg,
    const float* __restrict__ pwg, const float* __restrict__ pbg,
    float* __restrict__ out)
{
    const int b = blockIdx.x;
    const int t = threadIdx.x;

    __shared__ __align__(16) float xpad[30 * 30];      // x padded (zero border)
    __shared__ float w1s[16 * 9];
    __shared__ float b1s[16];
    // pooled conv1 output, zero-padded: [c][16 rows][18 cols], interior [1..14][1..14]
    // col stride 18: breaks the (2*py,2*px) stride-32-bank degeneracy of stride 16
    __shared__ __align__(16) float p1[16 * 16 * 18];
    __shared__ __align__(16) float w2t[16 * 9 * 32];   // [ic][k][oc] - oc contiguous
    __shared__ float b2s[32];
    __shared__ __align__(16) float p2[1568];           // flat (oc*49 + py*7 + px)
    __shared__ float ang[4];
    __shared__ float zsh[4];

    // ---------------- phase 0: stage inputs into LDS ----------------
    const float* xb = xg + (size_t)b * 784;
    for (int j = t; j < 900; j += 256) {
        int y = j / 30, x = j - y * 30;
        float v = 0.f;
        if (y >= 1 && y <= 28 && x >= 1 && x <= 28)
            v = xb[(y - 1) * 28 + (x - 1)];
        xpad[j] = v;
    }
    if (t < 144) w1s[t] = w1g[t];
    if (t < 16)  b1s[t] = b1g[t];
    if (t < 32)  b2s[t] = b2g[t];
    for (int j = t; j < 4608; j += 256) {   // conv2_w: [oc][ic][ky][kx] -> [ic*9+k][oc]
        int oc = j / 144, r = j - oc * 144;
        w2t[r * 32 + oc] = w2g[j];
    }
    for (int j = t; j < 16 * 16 * 18; j += 256) p1[j] = 0.f;  // zero incl. borders
    __syncthreads();

    // ---------------- phase 1: conv1 + relu + 2x2 maxpool -> p1 ----------------
    {
        int c = t >> 4, s = t & 15;         // 16 threads per channel
        float wt[9];
        #pragma unroll
        for (int k = 0; k < 9; ++k) wt[k] = w1s[c * 9 + k];
        float bias = b1s[c];
        for (int pp = 0; pp < 13; ++pp) {   // 196 pooled pixels / 16
            int p = s + (pp << 4);
            if (p < 196) {
                int py = p / 14, px = p - py * 14;
                int y0 = py * 2, x0 = px * 2;
                float a[4][4];
                #pragma unroll
                for (int r = 0; r < 4; ++r)
                    #pragma unroll
                    for (int cc = 0; cc < 4; ++cc)
                        a[r][cc] = xpad[(y0 + r) * 30 + x0 + cc];
                float s00 = bias, s01 = bias, s10 = bias, s11 = bias;
                #pragma unroll
                for (int ky = 0; ky < 3; ++ky)
                    #pragma unroll
                    for (int kx = 0; kx < 3; ++kx) {
                        float w = wt[ky * 3 + kx];
                        s00 = fmaf(w, a[ky][kx],         s00);
                        s01 = fmaf(w, a[ky][kx + 1],     s01);
                        s10 = fmaf(w, a[ky + 1][kx],     s10);
                        s11 = fmaf(w, a[ky + 1][kx + 1], s11);
                    }
                float v = fmaxf(fmaxf(s00, s01), fmaxf(s10, s11));
                v = fmaxf(v, 0.f);          // relu then maxpool == max(0, ...)
                p1[c * 288 + (py + 1) * 18 + (px + 1)] = v;
            }
        }
    }
    __syncthreads();

    // ---------------- phase 2: conv2 + relu + 2x2 maxpool -> p2 ----------------
    // thread -> (oc group of 8, pooled pixel); 4*49 = 196 active threads
    if (t < 196) {
        int ocg = t / 49, p = t - ocg * 49;
        int py = p / 7, px = p - py * 7;
        int oc0 = ocg * 8;
        float acc[4][8];
        #pragma unroll
        for (int o = 0; o < 8; ++o) {
            float bb = b2s[oc0 + o];
            acc[0][o] = bb; acc[1][o] = bb; acc[2][o] = bb; acc[3][o] = bb;
        }
        int ybase = py * 2, xbase = px * 2;  // padded coords of 4x4 input patch
        for (int ic = 0; ic < 16; ++ic) {
            const float* pch = &p1[ic * 288 + ybase * 18 + xbase];
            float a[4][4];
            #pragma unroll
            for (int r = 0; r < 4; ++r)
                #pragma unroll
                for (int cc = 0; cc < 4; ++cc)
                    a[r][cc] = pch[r * 18 + cc];
            const float* wp = &w2t[ic * 288 + oc0];
            #pragma unroll
            for (int k = 0; k < 9; ++k) {
                int ky = k / 3, kx = k - ky * 3;
                float4 wv0 = *(const float4*)(wp + k * 32);
                float4 wv1 = *(const float4*)(wp + k * 32 + 4);
                float wv[8] = {wv0.x, wv0.y, wv0.z, wv0.w,
                               wv1.x, wv1.y, wv1.z, wv1.w};
                #pragma unroll
                for (int o = 0; o < 8; ++o) {
                    float w = wv[o];
                    acc[0][o] = fmaf(w, a[ky][kx],         acc[0][o]);
                    acc[1][o] = fmaf(w, a[ky][kx + 1],     acc[1][o]);
                    acc[2][o] = fmaf(w, a[ky + 1][kx],     acc[2][o]);
                    acc[3][o] = fmaf(w, a[ky + 1][kx + 1], acc[3][o]);
                }
            }
        }
        #pragma unroll
        for (int o = 0; o < 8; ++o) {
            float v = fmaxf(fmaxf(acc[0][o], acc[1][o]), fmaxf(acc[2][o], acc[3][o]));
            v = fmaxf(v, 0.f);
            p2[(oc0 + o) * 49 + p] = v;
        }
    }
    __syncthreads();

    // ---------------- phase 3: dense (1568 -> 4), one output per wave ----------------
    {
        int w = t >> 6, lane = t & 63;
        const float* dw = dwg + w * 1568;
        float partial = 0.f;
        for (int i = lane; i < 1568; i += 64)
            partial = fmaf(p2[i], dw[i], partial);
        #pragma unroll
        for (int m = 32; m >= 1; m >>= 1)
            partial += __shfl_xor(partial, m, 64);
        if (lane == 0) ang[w] = partial + dbg[w];
    }
    __syncthreads();

    // ---------------- phase 4: 4-qubit statevector sim (wave 0, amp per lane) ----------------
    if (t < 64) {
        int l = t & 15;                      // basis index; wire w -> bit (3-w)
        float re = (l == 0) ? 1.f : 0.f;
        float im = 0.f;
        // initial RY(angles * pi) on each wire
        #pragma unroll
        for (int w = 0; w < 4; ++w) {
            float th = ang[w] * (PI_F * 0.5f);   // theta/2
            float c = cosf(th), s = sinf(th);
            gate1(re, im, l, w, C2{c, 0.f}, C2{-s, 0.f}, C2{s, 0.f}, C2{c, 0.f});
        }
        for (int layer = 0; layer < 2; ++layer) {
            int st = layer * 18;
            #pragma unroll
            for (int q = 0; q < 4; ++q) {    // M = RZ(a2) @ RY(a1) @ RX(a0)
                float a0 = qpg[st + 3 * q], a1 = qpg[st + 3 * q + 1], a2 = qpg[st + 3 * q + 2];
                float cx = cosf(0.5f * a0), sx = sinf(0.5f * a0);
                float cy = cosf(0.5f * a1), sy = sinf(0.5f * a1);
                float cz = cosf(0.5f * a2), sz = sinf(0.5f * a2);
                C2 T00{cy * cx,  sy * sx}, T01{-sy * cx, -cy * sx};
                C2 T10{sy * cx, -cy * sx}, T11{ cy * cx, -sy * sx};
                C2 E0{cz, -sz}, E1{cz, sz};
                gate1(re, im, l, q, cmul(E0, T00), cmul(E0, T01),
                                      cmul(E1, T10), cmul(E1, T11));
            }
            const int pi_[6] = {0, 0, 0, 1, 1, 2};
            const int pj_[6] = {1, 2, 3, 2, 3, 3};
            #pragma unroll
            for (int k = 0; k < 6; ++k) {    // CNOT(i->j) then RZ(e) on j
                int i = pi_[k], j = pj_[k];
                float e = qpg[st + 12 + k];
                int maskj = 1 << (3 - j);
                float pre = __shfl_xor(re, maskj, 64);
                float pim = __shfl_xor(im, maskj, 64);
                bool bi = ((l >> (3 - i)) & 1) != 0;
                re = bi ? pre : re;
                im = bi ? pim : im;
                float ce = cosf(0.5f * e), se = sinf(0.5f * e);
                bool bj = (l & maskj) != 0;
                C2 ph{ce, bj ? se : -se};
                C2 r = cmul(C2{re, im}, ph);
                re = r.x; im = r.y;
            }
        }
        // expectation <Z_w> = sum |amp|^2 * (1 - 2*bit_w)
        float pr = re * re + im * im;
        float z0 = ((l >> 3) & 1) ? -pr : pr;
        float z1 = ((l >> 2) & 1) ? -pr : pr;
        float z2 = ((l >> 1) & 1) ? -pr : pr;
        float z3 = (l & 1)        ? -pr : pr;
        #pragma unroll
        for (int m = 1; m <= 8; m <<= 1) {
            z0 += __shfl_xor(z0, m, 64);
            z1 += __shfl_xor(z1, m, 64);
            z2 += __shfl_xor(z2, m, 64);
            z3 += __shfl_xor(z3, m, 64);
        }
        if (t == 0) { zsh[0] = z0; zsh[1] = z1; zsh[2] = z2; zsh[3] = z3; }
    }
    __syncthreads();

    // ---------------- phase 5: post linear (4 -> 10) ----------------
    if (t < 10) {
        float o = pbg[t];
        #pragma unroll
        for (int w = 0; w < 4; ++w)
            o = fmaf(zsh[w], pwg[t * 4 + w], o);
        out[(size_t)b * 10 + t] = o;
    }
}

extern "C" void kernel_launch(void* const* d_in, const int* in_sizes, int n_in,
                              void* d_out, int out_size, void* d_ws, size_t ws_size,
                              hipStream_t stream) {
    const float* x  = (const float*)d_in[0];
    const float* w1 = (const float*)d_in[1];
    const float* b1 = (const float*)d_in[2];
    const float* w2 = (const float*)d_in[3];
    const float* b2 = (const float*)d_in[4];
    const float* dw = (const float*)d_in[5];
    const float* db = (const float*)d_in[6];
    const float* qp = (const float*)d_in[7];
    const float* pw = (const float*)d_in[8];
    const float* pb = (const float*)d_in[9];
    float* out = (float*)d_out;
    int B = in_sizes[0] / 784;   // 4096
    qnn_fused<<<B, 256, 0, stream>>>(x, w1, b1, w2, b2, dw, db, qp, pw, pb, out);
}

// Round 2
// 202.162 us; speedup vs baseline: 1.3291x; 1.3291x over previous
//
#include <hip/hip_runtime.h>

#define PI_F 3.14159265358979323846f

struct C2 { float x, y; };
__device__ __forceinline__ C2 cmul(C2 a, C2 b) {
    return C2{a.x * b.x - a.y * b.y, a.x * b.y + a.y * b.x};
}

// Apply 2x2 (possibly complex) gate M on wire w to the statevector held one
// amplitude per lane (lane l = basis index, bit of wire w is bit (3-w) of l).
__device__ __forceinline__ void gate1(float& re, float& im, int l, int w,
                                      C2 m00, C2 m01, C2 m10, C2 m11) {
    int mask = 1 << (3 - w);
    float pre = __shfl_xor(re, mask, 64);
    float pim = __shfl_xor(im, mask, 64);
    bool b = (l & mask) != 0;
    C2 d = b ? m11 : m00;
    C2 o = b ? m10 : m01;
    float nre = d.x * re - d.y * im + o.x * pre - o.y * pim;
    float nim = d.x * im + d.y * re + o.x * pim + o.y * pre;
    re = nre; im = nim;
}

// p1 layout: [c][16 rows][20 cols] fp32. Row stride 20 => conv-patch b64 reads
// hit banks (8*py + 20*r + 2*px) mod 32 -> worst 2-way aliasing (free).
#define P1_RS 20
#define P1_CS (16 * P1_RS)   // 320

__global__ __launch_bounds__(256, 5) void qnn_fused(
    const float* __restrict__ xg,
    const float* __restrict__ w1g, const float* __restrict__ b1g,
    const float* __restrict__ w2g, const float* __restrict__ b2g,
    const float* __restrict__ dwg, const float* __restrict__ dbg,
    const float* __restrict__ qpg,
    const float* __restrict__ pwg, const float* __restrict__ pbg,
    float* __restrict__ out)
{
    const int b = blockIdx.x;
    const int t = threadIdx.x;

    __shared__ __align__(16) float xpad[30 * 30];         // x padded (zero border)
    __shared__ float w1s[16 * 9];
    __shared__ float b1s[16];
    __shared__ __align__(16) float p1[16 * P1_CS];        // 20480 B
    __shared__ __align__(16) float p2[1568];              // flat (oc*49 + py*7 + px)
    __shared__ float ang[4];
    __shared__ float zsh[4];

    // ---------------- phase 0: stage inputs into LDS ----------------
    const float* xb = xg + (size_t)b * 784;
    for (int j = t; j < 900; j += 256) {
        int y = j / 30, x = j - y * 30;
        float v = 0.f;
        if (y >= 1 && y <= 28 && x >= 1 && x <= 28)
            v = xb[(y - 1) * 28 + (x - 1)];
        xpad[j] = v;
    }
    if (t < 144) w1s[t] = w1g[t];
    if (t < 16)  b1s[t] = b1g[t];
    for (int j = t; j < 16 * P1_CS; j += 256) p1[j] = 0.f;  // zero incl. borders
    __syncthreads();

    // ---------------- phase 1: conv1 + relu + 2x2 maxpool -> p1 ----------------
    {
        int c = t >> 4, s = t & 15;         // 16 threads per channel
        float wt[9];
        #pragma unroll
        for (int k = 0; k < 9; ++k) wt[k] = w1s[c * 9 + k];
        float bias = b1s[c];
        for (int pp = 0; pp < 13; ++pp) {   // 196 pooled pixels / 16
            int p = s + (pp << 4);
            if (p < 196) {
                int py = p / 14, px = p - py * 14;
                int y0 = py * 2, x0 = px * 2;   // even -> float2 aligned
                float a[4][4];
                #pragma unroll
                for (int r = 0; r < 4; ++r) {
                    float2 v0 = *(const float2*)&xpad[(y0 + r) * 30 + x0];
                    float2 v1 = *(const float2*)&xpad[(y0 + r) * 30 + x0 + 2];
                    a[r][0] = v0.x; a[r][1] = v0.y; a[r][2] = v1.x; a[r][3] = v1.y;
                }
                float s00 = bias, s01 = bias, s10 = bias, s11 = bias;
                #pragma unroll
                for (int ky = 0; ky < 3; ++ky)
                    #pragma unroll
                    for (int kx = 0; kx < 3; ++kx) {
                        float w = wt[ky * 3 + kx];
                        s00 = fmaf(w, a[ky][kx],         s00);
                        s01 = fmaf(w, a[ky][kx + 1],     s01);
                        s10 = fmaf(w, a[ky + 1][kx],     s10);
                        s11 = fmaf(w, a[ky + 1][kx + 1], s11);
                    }
                float v = fmaxf(fmaxf(s00, s01), fmaxf(s10, s11));
                v = fmaxf(v, 0.f);          // relu then maxpool == max(0, ...)
                p1[c * P1_CS + (py + 1) * P1_RS + (px + 1)] = v;
            }
        }
    }
    __syncthreads();

    // ---------------- phase 2: conv2 + relu + 2x2 maxpool -> p2 ----------------
    // wave = oc-group of 8 (wave-uniform -> weights via scalar cache),
    // lane = pooled pixel (49 of 64 active)
    {
        int wv = __builtin_amdgcn_readfirstlane(t >> 6);  // 0..3, SGPR
        int oc0 = wv * 8;
        int lane = t & 63;
        if (lane < 49) {
            int p = lane;
            int py = p / 7, px = p - py * 7;
            float acc[4][8];
            #pragma unroll
            for (int o = 0; o < 8; ++o) {
                float bb = b2g[oc0 + o];                  // s_load
                acc[0][o] = bb; acc[1][o] = bb; acc[2][o] = bb; acc[3][o] = bb;
            }
            int ybase = py * 2, xbase = px * 2;           // padded coords, even
            for (int ic = 0; ic < 16; ++ic) {
                const float* pch = &p1[ic * P1_CS + ybase * P1_RS + xbase];
                float a[4][4];
                #pragma unroll
                for (int r = 0; r < 4; ++r) {
                    float2 v0 = *(const float2*)(pch + r * P1_RS);
                    float2 v1 = *(const float2*)(pch + r * P1_RS + 2);
                    a[r][0] = v0.x; a[r][1] = v0.y; a[r][2] = v1.x; a[r][3] = v1.y;
                }
                #pragma unroll
                for (int o = 0; o < 8; ++o) {
                    const float* wp = w2g + (oc0 + o) * 144 + ic * 9;  // uniform
                    float wk[9];
                    #pragma unroll
                    for (int k = 0; k < 9; ++k) wk[k] = wp[k];         // s_load
                    #pragma unroll
                    for (int ky = 0; ky < 3; ++ky)
                        #pragma unroll
                        for (int kx = 0; kx < 3; ++kx) {
                            float w = wk[ky * 3 + kx];
                            acc[0][o] = fmaf(w, a[ky][kx],         acc[0][o]);
                            acc[1][o] = fmaf(w, a[ky][kx + 1],     acc[1][o]);
                            acc[2][o] = fmaf(w, a[ky + 1][kx],     acc[2][o]);
                            acc[3][o] = fmaf(w, a[ky + 1][kx + 1], acc[3][o]);
                        }
                }
            }
            #pragma unroll
            for (int o = 0; o < 8; ++o) {
                float v = fmaxf(fmaxf(acc[0][o], acc[1][o]), fmaxf(acc[2][o], acc[3][o]));
                v = fmaxf(v, 0.f);
                p2[(oc0 + o) * 49 + p] = v;
            }
        }
    }
    __syncthreads();

    // ---------------- phase 3: dense (1568 -> 4), one output per wave ----------------
    {
        int w = t >> 6, lane = t & 63;
        const float* dw = dwg + w * 1568;
        float partial = 0.f;
        for (int i = lane; i < 1568; i += 64)
            partial = fmaf(p2[i], dw[i], partial);
        #pragma unroll
        for (int m = 32; m >= 1; m >>= 1)
            partial += __shfl_xor(partial, m, 64);
        if (lane == 0) ang[w] = partial + dbg[w];
    }
    __syncthreads();

    // ---------------- phase 4: 4-qubit statevector sim (wave 0, amp per lane) ----------------
    if (t < 64) {
        int l = t & 15;                      // basis index; wire w -> bit (3-w)
        float re = (l == 0) ? 1.f : 0.f;
        float im = 0.f;
        // initial RY(angles * pi) on each wire
        #pragma unroll
        for (int w = 0; w < 4; ++w) {
            float th = ang[w] * (PI_F * 0.5f);   // theta/2
            float c = cosf(th), s = sinf(th);
            gate1(re, im, l, w, C2{c, 0.f}, C2{-s, 0.f}, C2{s, 0.f}, C2{c, 0.f});
        }
        for (int layer = 0; layer < 2; ++layer) {
            int st = layer * 18;
            #pragma unroll
            for (int q = 0; q < 4; ++q) {    // M = RZ(a2) @ RY(a1) @ RX(a0)
                float a0 = qpg[st + 3 * q], a1 = qpg[st + 3 * q + 1], a2 = qpg[st + 3 * q + 2];
                float cx = cosf(0.5f * a0), sx = sinf(0.5f * a0);
                float cy = cosf(0.5f * a1), sy = sinf(0.5f * a1);
                float cz = cosf(0.5f * a2), sz = sinf(0.5f * a2);
                C2 T00{cy * cx,  sy * sx}, T01{-sy * cx, -cy * sx};
                C2 T10{sy * cx, -cy * sx}, T11{ cy * cx, -sy * sx};
                C2 E0{cz, -sz}, E1{cz, sz};
                gate1(re, im, l, q, cmul(E0, T00), cmul(E0, T01),
                                      cmul(E1, T10), cmul(E1, T11));
            }
            const int pi_[6] = {0, 0, 0, 1, 1, 2};
            const int pj_[6] = {1, 2, 3, 2, 3, 3};
            #pragma unroll
            for (int k = 0; k < 6; ++k) {    // CNOT(i->j) then RZ(e) on j
                int i = pi_[k], j = pj_[k];
                float e = qpg[st + 12 + k];
                int maskj = 1 << (3 - j);
                float pre = __shfl_xor(re, maskj, 64);
                float pim = __shfl_xor(im, maskj, 64);
                bool bi = ((l >> (3 - i)) & 1) != 0;
                re = bi ? pre : re;
                im = bi ? pim : im;
                float ce = cosf(0.5f * e), se = sinf(0.5f * e);
                bool bj = (l & maskj) != 0;
                C2 ph{ce, bj ? se : -se};
                C2 r = cmul(C2{re, im}, ph);
                re = r.x; im = r.y;
            }
        }
        // expectation <Z_w> = sum |amp|^2 * (1 - 2*bit_w)
        float pr = re * re + im * im;
        float z0 = ((l >> 3) & 1) ? -pr : pr;
        float z1 = ((l >> 2) & 1) ? -pr : pr;
        float z2 = ((l >> 1) & 1) ? -pr : pr;
        float z3 = (l & 1)        ? -pr : pr;
        #pragma unroll
        for (int m = 1; m <= 8; m <<= 1) {
            z0 += __shfl_xor(z0, m, 64);
            z1 += __shfl_xor(z1, m, 64);
            z2 += __shfl_xor(z2, m, 64);
            z3 += __shfl_xor(z3, m, 64);
        }
        if (t == 0) { zsh[0] = z0; zsh[1] = z1; zsh[2] = z2; zsh[3] = z3; }
    }
    __syncthreads();

    // ---------------- phase 5: post linear (4 -> 10) ----------------
    if (t < 10) {
        float o = pbg[t];
        #pragma unroll
        for (int w = 0; w < 4; ++w)
            o = fmaf(zsh[w], pwg[t * 4 + w], o);
        out[(size_t)b * 10 + t] = o;
    }
}

extern "C" void kernel_launch(void* const* d_in, const int* in_sizes, int n_in,
                              void* d_out, int out_size, void* d_ws, size_t ws_size,
                              hipStream_t stream) {
    const float* x  = (const float*)d_in[0];
    const float* w1 = (const float*)d_in[1];
    const float* b1 = (const float*)d_in[2];
    const float* w2 = (const float*)d_in[3];
    const float* b2 = (const float*)d_in[4];
    const float* dw = (const float*)d_in[5];
    const float* db = (const float*)d_in[6];
    const float* qp = (const float*)d_in[7];
    const float* pw = (const float*)d_in[8];
    const float* pb = (const float*)d_in[9];
    float* out = (float*)d_out;
    int B = in_sizes[0] / 784;   // 4096
    qnn_fused<<<B, 256, 0, stream>>>(x, w1, b1, w2, b2, dw, db, qp, pw, pb, out);
}

// Round 3
// 173.381 us; speedup vs baseline: 1.5497x; 1.1660x over previous
//
#include <hip/hip_runtime.h>

#define PI_F 3.14159265358979323846f

struct C2 { float x, y; };
__device__ __forceinline__ C2 cmul(C2 a, C2 b) {
    return C2{a.x * b.x - a.y * b.y, a.x * b.y + a.y * b.x};
}

// Apply 2x2 complex gate M on wire w; one amplitude per lane (l = basis index,
// wire w is bit (3-w) of l).
__device__ __forceinline__ void gate1(float& re, float& im, int l, int w,
                                      C2 m00, C2 m01, C2 m10, C2 m11) {
    int mask = 1 << (3 - w);
    float pre = __shfl_xor(re, mask, 64);
    float pim = __shfl_xor(im, mask, 64);
    bool b = (l & mask) != 0;
    C2 d = b ? m11 : m00;
    C2 o = b ? m10 : m01;
    float nre = d.x * re - d.y * im + o.x * pre - o.y * pim;
    float nim = d.x * im + d.y * re + o.x * pim + o.y * pre;
    re = nre; im = nim;
}

// p1 layout: [c][16 rows][20 cols] fp32 (stride 20 keeps b64 patch reads ~2-way).
#define P1_RS 20
#define P1_CS (16 * P1_RS)   // 320

// ws layout (floats):
//   [0 .. 6143]   U: winograd-1D transformed conv2 weights,
//                 idx = ((ic*4 + ocg)*12 + ky*4 + j)*8 + (oc&7)
//   [6144..6207]  rot gates: (layer*4+q)*8 + {m00.x,m00.y,m01.x,m01.y,m10.x,m10.y,m11.x,m11.y}
//   [6208..6231]  ent gates: (layer*6+k)*2 + {cos(e/2), sin(e/2)}
#define WS_GROT 6144
#define WS_GENT 6208

// ---------------- prologue: batch-invariant precompute ----------------
__global__ __launch_bounds__(256) void qnn_prep(
    const float* __restrict__ w2g, const float* __restrict__ qpg,
    float* __restrict__ ws)
{
    int t = threadIdx.x;
    // conv2 weight 1D-winograd transform (along x): u = G g per row.
    for (int pp = t; pp < 512; pp += 256) {
        int ic = pp >> 5, oc = pp & 31;
        const float* g = w2g + oc * 144 + ic * 9;
        int ocg = oc >> 3, o = oc & 7;
        float* u = ws + (size_t)((ic * 4 + ocg) * 12) * 8 + o;
        #pragma unroll
        for (int ky = 0; ky < 3; ++ky) {
            float g0 = g[ky * 3], g1 = g[ky * 3 + 1], g2 = g[ky * 3 + 2];
            u[(ky * 4 + 0) * 8] = g0;
            u[(ky * 4 + 1) * 8] = 0.5f * (g0 + g1 + g2);
            u[(ky * 4 + 2) * 8] = 0.5f * (g0 - g1 + g2);
            u[(ky * 4 + 3) * 8] = g2;
        }
    }
    if (t < 8) {                     // rot gate matrices: M = RZ(a2) RY(a1) RX(a0)
        int layer = t >> 2, q = t & 3;
        int st = layer * 18;
        float a0 = qpg[st + 3 * q], a1 = qpg[st + 3 * q + 1], a2 = qpg[st + 3 * q + 2];
        float cx = cosf(0.5f * a0), sx = sinf(0.5f * a0);
        float cy = cosf(0.5f * a1), sy = sinf(0.5f * a1);
        float cz = cosf(0.5f * a2), sz = sinf(0.5f * a2);
        C2 T00{cy * cx,  sy * sx}, T01{-sy * cx, -cy * sx};
        C2 T10{sy * cx, -cy * sx}, T11{ cy * cx, -sy * sx};
        C2 E0{cz, -sz}, E1{cz, sz};
        C2 m00 = cmul(E0, T00), m01 = cmul(E0, T01);
        C2 m10 = cmul(E1, T10), m11 = cmul(E1, T11);
        float* gm = ws + WS_GROT + t * 8;
        gm[0] = m00.x; gm[1] = m00.y; gm[2] = m01.x; gm[3] = m01.y;
        gm[4] = m10.x; gm[5] = m10.y; gm[6] = m11.x; gm[7] = m11.y;
    }
    if (t >= 32 && t < 44) {         // entangler RZ phases
        int k = t - 32;              // k = layer*6 + kk
        float e = qpg[(k / 6) * 18 + 12 + (k % 6)];
        ws[WS_GENT + k * 2]     = cosf(0.5f * e);
        ws[WS_GENT + k * 2 + 1] = sinf(0.5f * e);
    }
}

__global__ __launch_bounds__(256, 4) void qnn_fused(
    const float* __restrict__ xg,
    const float* __restrict__ w1g, const float* __restrict__ b1g,
    const float* __restrict__ b2g,
    const float* __restrict__ dwg, const float* __restrict__ dbg,
    const float* __restrict__ wsc,      // precomputed U + gates
    const float* __restrict__ pwg, const float* __restrict__ pbg,
    float* __restrict__ out)
{
    const int b = blockIdx.x;
    const int t = threadIdx.x;

    __shared__ __align__(16) float xpad[30 * 30];         // x padded (zero border)
    __shared__ float w1s[16 * 9];
    __shared__ float b1s[16];
    __shared__ __align__(16) float p1[16 * P1_CS];        // 20480 B
    __shared__ __align__(16) float p2[1568];              // (oc*49 + py*7 + px)
    __shared__ float ang[4];
    __shared__ float zsh[4];

    // ---------------- phase 0: stage into LDS ----------------
    const float* xb = xg + (size_t)b * 784;
    for (int j = t; j < 900; j += 256) {
        int y = j / 30, x = j - y * 30;
        float v = 0.f;
        if (y >= 1 && y <= 28 && x >= 1 && x <= 28)
            v = xb[(y - 1) * 28 + (x - 1)];
        xpad[j] = v;
    }
    if (t < 144) w1s[t] = w1g[t];
    if (t < 16)  b1s[t] = b1g[t];
    {   // zero p1 (incl. borders) with b128 stores: 1280 float4 / 256 = 5 iters
        float4 z4 = {0.f, 0.f, 0.f, 0.f};
        float4* p4 = (float4*)p1;
        #pragma unroll
        for (int j = 0; j < 5; ++j) p4[t + j * 256] = z4;
    }
    __syncthreads();

    // ---------------- phase 1: conv1 + relu + 2x2 maxpool -> p1 ----------------
    {
        int c = t >> 4, s = t & 15;         // 16 threads per channel
        float wt[9];
        #pragma unroll
        for (int k = 0; k < 9; ++k) wt[k] = w1s[c * 9 + k];
        float bias = b1s[c];
        for (int pp = 0; pp < 13; ++pp) {   // 196 pooled pixels / 16
            int p = s + (pp << 4);
            if (p < 196) {
                int py = p / 14, px = p - py * 14;
                int y0 = py * 2, x0 = px * 2;   // even -> float2 aligned
                float a[4][4];
                #pragma unroll
                for (int r = 0; r < 4; ++r) {
                    float2 v0 = *(const float2*)&xpad[(y0 + r) * 30 + x0];
                    float2 v1 = *(const float2*)&xpad[(y0 + r) * 30 + x0 + 2];
                    a[r][0] = v0.x; a[r][1] = v0.y; a[r][2] = v1.x; a[r][3] = v1.y;
                }
                float s00 = bias, s01 = bias, s10 = bias, s11 = bias;
                #pragma unroll
                for (int ky = 0; ky < 3; ++ky)
                    #pragma unroll
                    for (int kx = 0; kx < 3; ++kx) {
                        float w = wt[ky * 3 + kx];
                        s00 = fmaf(w, a[ky][kx],         s00);
                        s01 = fmaf(w, a[ky][kx + 1],     s01);
                        s10 = fmaf(w, a[ky + 1][kx],     s10);
                        s11 = fmaf(w, a[ky + 1][kx + 1], s11);
                    }
                float v = fmaxf(fmaxf(s00, s01), fmaxf(s10, s11));
                v = fmaxf(v, 0.f);
                p1[c * P1_CS + (py + 1) * P1_RS + (px + 1)] = v;
            }
        }
    }
    __syncthreads();

    // ---------------- phase 2: conv2 (1D winograd-x) + relu + pool -> p2 ------
    // wave = oc-group of 8 (uniform -> transformed weights via scalar cache),
    // lane = pooled pixel (49 of 64 active). Accumulate in x-transform domain:
    // macc[yy][j][oc] += U[ic][ky][j][oc] * v[yy+ky][j], inverse at the end.
    {
        int wv = __builtin_amdgcn_readfirstlane(t >> 6);  // 0..3
        int oc0 = wv * 8;
        int lane = t & 63;
        if (lane < 49) {
            int p = lane;
            int py = p / 7, px = p - py * 7;
            float macc[2][4][8];
            #pragma unroll
            for (int yy = 0; yy < 2; ++yy)
                #pragma unroll
                for (int j = 0; j < 4; ++j)
                    #pragma unroll
                    for (int o = 0; o < 8; ++o) macc[yy][j][o] = 0.f;
            int ybase = py * 2, xbase = px * 2;           // padded coords, even
            for (int ic = 0; ic < 16; ++ic) {
                const float* pch = &p1[ic * P1_CS + ybase * P1_RS + xbase];
                float d[4][4];
                #pragma unroll
                for (int r = 0; r < 4; ++r) {
                    float2 v0 = *(const float2*)(pch + r * P1_RS);
                    float2 v1 = *(const float2*)(pch + r * P1_RS + 2);
                    d[r][0] = v0.x; d[r][1] = v0.y; d[r][2] = v1.x; d[r][3] = v1.y;
                }
                float v[4][4];                            // B^T d per row
                #pragma unroll
                for (int r = 0; r < 4; ++r) {
                    v[r][0] = d[r][0] - d[r][2];
                    v[r][1] = d[r][1] + d[r][2];
                    v[r][2] = d[r][2] - d[r][1];
                    v[r][3] = d[r][1] - d[r][3];
                }
                const float* up = wsc + (size_t)((ic * 4 + wv) * 12) * 8;  // uniform
                #pragma unroll
                for (int o = 0; o < 8; ++o)
                    #pragma unroll
                    for (int ky = 0; ky < 3; ++ky)
                        #pragma unroll
                        for (int j = 0; j < 4; ++j) {
                            float u = up[(ky * 4 + j) * 8 + o];   // s_load
                            macc[0][j][o] = fmaf(u, v[ky][j],     macc[0][j][o]);
                            macc[1][j][o] = fmaf(u, v[ky + 1][j], macc[1][j][o]);
                        }
            }
            #pragma unroll
            for (int o = 0; o < 8; ++o) {                 // inverse: A^T m
                float o00 = macc[0][0][o] + macc[0][1][o] + macc[0][2][o];
                float o01 = macc[0][1][o] - macc[0][2][o] - macc[0][3][o];
                float o10 = macc[1][0][o] + macc[1][1][o] + macc[1][2][o];
                float o11 = macc[1][1][o] - macc[1][2][o] - macc[1][3][o];
                float m4 = fmaxf(fmaxf(o00, o01), fmaxf(o10, o11)) + b2g[oc0 + o];
                p2[(oc0 + o) * 49 + p] = fmaxf(m4, 0.f);
            }
        }
    }
    __syncthreads();

    // ---------------- phase 3: dense (1568 -> 4), one output per wave --------
    {
        int w = t >> 6, lane = t & 63;
        const float* dw = dwg + w * 1568;
        float partial = 0.f;
        for (int i = lane; i < 1568; i += 64)
            partial = fmaf(p2[i], dw[i], partial);
        #pragma unroll
        for (int m = 32; m >= 1; m >>= 1)
            partial += __shfl_xor(partial, m, 64);
        if (lane == 0) ang[w] = partial + dbg[w];
    }
    __syncthreads();

    // ---------------- phase 4: 4-qubit statevector (wave 0) ----------------
    if (t < 64) {
        int l = t & 15;
        float re = (l == 0) ? 1.f : 0.f;
        float im = 0.f;
        #pragma unroll
        for (int w = 0; w < 4; ++w) {        // initial RY(angle * pi)
            float th = ang[w] * (PI_F * 0.5f);
            float c = cosf(th), s = sinf(th);
            gate1(re, im, l, w, C2{c, 0.f}, C2{-s, 0.f}, C2{s, 0.f}, C2{c, 0.f});
        }
        #pragma unroll
        for (int layer = 0; layer < 2; ++layer) {
            #pragma unroll
            for (int q = 0; q < 4; ++q) {    // precomputed rot gates (uniform)
                const float* gm = wsc + WS_GROT + (layer * 4 + q) * 8;
                gate1(re, im, l, q, C2{gm[0], gm[1]}, C2{gm[2], gm[3]},
                                     C2{gm[4], gm[5]}, C2{gm[6], gm[7]});
            }
            const int pi_[6] = {0, 0, 0, 1, 1, 2};
            const int pj_[6] = {1, 2, 3, 2, 3, 3};
            #pragma unroll
            for (int k = 0; k < 6; ++k) {    // CNOT(i->j) then RZ on j
                int i = pi_[k], j = pj_[k];
                const float* em = wsc + WS_GENT + (layer * 6 + k) * 2;
                float ce = em[0], se = em[1];
                int maskj = 1 << (3 - j);
                float pre = __shfl_xor(re, maskj, 64);
                float pim = __shfl_xor(im, maskj, 64);
                bool bi = ((l >> (3 - i)) & 1) != 0;
                re = bi ? pre : re;
                im = bi ? pim : im;
                bool bj = (l & maskj) != 0;
                C2 ph{ce, bj ? se : -se};
                C2 r = cmul(C2{re, im}, ph);
                re = r.x; im = r.y;
            }
        }
        float pr = re * re + im * im;
        float z0 = ((l >> 3) & 1) ? -pr : pr;
        float z1 = ((l >> 2) & 1) ? -pr : pr;
        float z2 = ((l >> 1) & 1) ? -pr : pr;
        float z3 = (l & 1)        ? -pr : pr;
        #pragma unroll
        for (int m = 1; m <= 8; m <<= 1) {
            z0 += __shfl_xor(z0, m, 64);
            z1 += __shfl_xor(z1, m, 64);
            z2 += __shfl_xor(z2, m, 64);
            z3 += __shfl_xor(z3, m, 64);
        }
        if (t == 0) { zsh[0] = z0; zsh[1] = z1; zsh[2] = z2; zsh[3] = z3; }
    }
    __syncthreads();

    // ---------------- phase 5: post linear (4 -> 10) ----------------
    if (t < 10) {
        float o = pbg[t];
        #pragma unroll
        for (int w = 0; w < 4; ++w)
            o = fmaf(zsh[w], pwg[t * 4 + w], o);
        out[(size_t)b * 10 + t] = o;
    }
}

extern "C" void kernel_launch(void* const* d_in, const int* in_sizes, int n_in,
                              void* d_out, int out_size, void* d_ws, size_t ws_size,
                              hipStream_t stream) {
    const float* x  = (const float*)d_in[0];
    const float* w1 = (const float*)d_in[1];
    const float* b1 = (const float*)d_in[2];
    const float* w2 = (const float*)d_in[3];
    const float* b2 = (const float*)d_in[4];
    const float* dw = (const float*)d_in[5];
    const float* db = (const float*)d_in[6];
    const float* qp = (const float*)d_in[7];
    const float* pw = (const float*)d_in[8];
    const float* pb = (const float*)d_in[9];
    float* out = (float*)d_out;
    float* ws  = (float*)d_ws;
    int B = in_sizes[0] / 784;   // 4096

    qnn_prep<<<1, 256, 0, stream>>>(w2, qp, ws);
    qnn_fused<<<B, 256, 0, stream>>>(x, w1, b1, b2, dw, db, ws, pw, pb, out);
}

// Round 4
// 166.567 us; speedup vs baseline: 1.6131x; 1.0409x over previous
//
#include <hip/hip_runtime.h>

#define PI_F 3.14159265358979323846f

typedef _Float16 half2v __attribute__((ext_vector_type(2)));

struct C2 { float x, y; };
__device__ __forceinline__ C2 cmul(C2 a, C2 b) {
    return C2{a.x * b.x - a.y * b.y, a.x * b.y + a.y * b.x};
}

// Apply 2x2 complex gate M on wire w; one amplitude per lane (l = basis index,
// wire w is bit (3-w) of l).
__device__ __forceinline__ void gate1(float& re, float& im, int l, int w,
                                      C2 m00, C2 m01, C2 m10, C2 m11) {
    int mask = 1 << (3 - w);
    float pre = __shfl_xor(re, mask, 64);
    float pim = __shfl_xor(im, mask, 64);
    bool b = (l & mask) != 0;
    C2 d = b ? m11 : m00;
    C2 o = b ? m10 : m01;
    float nre = d.x * re - d.y * im + o.x * pre - o.y * pim;
    float nim = d.x * im + d.y * re + o.x * pim + o.y * pre;
    re = nre; im = nim;
}

// p1h layout: [icp][16 rows][20 cols] of uint = half2 {ic=2*icp, ic=2*icp+1}.
#define P1_RS 20
#define P1_CS (16 * P1_RS)   // 320

// ws layout (floats):
//   [0 .. 3071]   U2: winograd-1D transformed conv2 weights, f16-pair packed:
//                 idx = ((icp*4 + ocg)*12 + ky*4 + j)*8 + (oc&7),
//                 value bits = half2{u(ic=2icp), u(ic=2icp+1)}
//   [6144..6207]  rot gates: (layer*4+q)*8 + {m00,m01,m10,m11 as re,im pairs}
//   [6208..6231]  ent gates: (layer*6+k)*2 + {cos(e/2), sin(e/2)}
#define WS_GROT 6144
#define WS_GENT 6208

// ---------------- prologue: batch-invariant precompute ----------------
__global__ __launch_bounds__(256) void qnn_prep(
    const float* __restrict__ w2g, const float* __restrict__ qpg,
    float* __restrict__ ws)
{
    int t = threadIdx.x;
    // conv2 weight 1D-winograd transform (along x), packed by ic-pair.
    if (t < 256) {
        int icp = t >> 5, oc = t & 31;
        int ocg = oc >> 3, o = oc & 7;
        const float* ga = w2g + oc * 144 + (2 * icp) * 9;
        const float* gb = ga + 9;
        float* u = ws + (size_t)((icp * 4 + ocg) * 12) * 8 + o;
        #pragma unroll
        for (int ky = 0; ky < 3; ++ky) {
            float a0 = ga[ky * 3], a1 = ga[ky * 3 + 1], a2 = ga[ky * 3 + 2];
            float b0 = gb[ky * 3], b1 = gb[ky * 3 + 1], b2 = gb[ky * 3 + 2];
            float ua[4] = {a0, 0.5f * (a0 + a1 + a2), 0.5f * (a0 - a1 + a2), a2};
            float ub[4] = {b0, 0.5f * (b0 + b1 + b2), 0.5f * (b0 - b1 + b2), b2};
            #pragma unroll
            for (int j = 0; j < 4; ++j) {
                half2v h;
                h.x = (_Float16)ua[j];
                h.y = (_Float16)ub[j];
                u[(ky * 4 + j) * 8] = __builtin_bit_cast(float, h);
            }
        }
    }
    if (t < 8) {                     // rot gate matrices: M = RZ(a2) RY(a1) RX(a0)
        int layer = t >> 2, q = t & 3;
        int st = layer * 18;
        float a0 = qpg[st + 3 * q], a1 = qpg[st + 3 * q + 1], a2 = qpg[st + 3 * q + 2];
        float cx = cosf(0.5f * a0), sx = sinf(0.5f * a0);
        float cy = cosf(0.5f * a1), sy = sinf(0.5f * a1);
        float cz = cosf(0.5f * a2), sz = sinf(0.5f * a2);
        C2 T00{cy * cx,  sy * sx}, T01{-sy * cx, -cy * sx};
        C2 T10{sy * cx, -cy * sx}, T11{ cy * cx, -sy * sx};
        C2 E0{cz, -sz}, E1{cz, sz};
        C2 m00 = cmul(E0, T00), m01 = cmul(E0, T01);
        C2 m10 = cmul(E1, T10), m11 = cmul(E1, T11);
        float* gm = ws + WS_GROT + t * 8;
        gm[0] = m00.x; gm[1] = m00.y; gm[2] = m01.x; gm[3] = m01.y;
        gm[4] = m10.x; gm[5] = m10.y; gm[6] = m11.x; gm[7] = m11.y;
    }
    if (t >= 32 && t < 44) {         // entangler RZ phases
        int k = t - 32;
        float e = qpg[(k / 6) * 18 + 12 + (k % 6)];
        ws[WS_GENT + k * 2]     = cosf(0.5f * e);
        ws[WS_GENT + k * 2 + 1] = sinf(0.5f * e);
    }
}

__global__ __launch_bounds__(256, 6) void qnn_fused(
    const float* __restrict__ xg,
    const float* __restrict__ w1g, const float* __restrict__ b1g,
    const float* __restrict__ b2g,
    const float* __restrict__ dwg, const float* __restrict__ dbg,
    const float* __restrict__ wsc,      // precomputed U2 + gates
    const float* __restrict__ pwg, const float* __restrict__ pbg,
    float* __restrict__ out)
{
    const int b = blockIdx.x;
    const int t = threadIdx.x;

    __shared__ __align__(16) float xpad[30 * 30];         // x padded (zero border)
    __shared__ float w1s[16 * 9];
    __shared__ float b1s[16];
    __shared__ __align__(16) unsigned p1h[8 * P1_CS];     // 10240 B, half2 per elem
    __shared__ __align__(16) float p2[1568];              // (oc*49 + py*7 + px)
    __shared__ float ang[4];
    __shared__ float zsh[4];

    // ---------------- phase 0: stage into LDS ----------------
    const float* xb = xg + (size_t)b * 784;
    for (int j = t; j < 900; j += 256) {
        int y = j / 30, x = j - y * 30;
        float v = 0.f;
        if (y >= 1 && y <= 28 && x >= 1 && x <= 28)
            v = xb[(y - 1) * 28 + (x - 1)];
        xpad[j] = v;
    }
    if (t < 144) w1s[t] = w1g[t];
    if (t < 16)  b1s[t] = b1g[t];
    {   // zero p1h (incl. borders): 2560 uints = 640 uint4
        uint4 z4 = {0u, 0u, 0u, 0u};
        uint4* p4 = (uint4*)p1h;
        #pragma unroll
        for (int j = 0; j < 3; ++j) {
            int i = t + j * 256;
            if (i < 640) p4[i] = z4;
        }
    }
    __syncthreads();

    // ---------------- phase 1: conv1 + relu + 2x2 maxpool -> p1h (f16) -------
    {
        int c = t >> 4, s = t & 15;         // 16 threads per channel
        float wt[9];
        #pragma unroll
        for (int k = 0; k < 9; ++k) wt[k] = w1s[c * 9 + k];
        float bias = b1s[c];
        for (int pp = 0; pp < 13; ++pp) {   // 196 pooled pixels / 16
            int p = s + (pp << 4);
            if (p < 196) {
                int py = p / 14, px = p - py * 14;
                int y0 = py * 2, x0 = px * 2;   // even -> float2 aligned
                float a[4][4];
                #pragma unroll
                for (int r = 0; r < 4; ++r) {
                    float2 v0 = *(const float2*)&xpad[(y0 + r) * 30 + x0];
                    float2 v1 = *(const float2*)&xpad[(y0 + r) * 30 + x0 + 2];
                    a[r][0] = v0.x; a[r][1] = v0.y; a[r][2] = v1.x; a[r][3] = v1.y;
                }
                float s00 = bias, s01 = bias, s10 = bias, s11 = bias;
                #pragma unroll
                for (int ky = 0; ky < 3; ++ky)
                    #pragma unroll
                    for (int kx = 0; kx < 3; ++kx) {
                        float w = wt[ky * 3 + kx];
                        s00 = fmaf(w, a[ky][kx],         s00);
                        s01 = fmaf(w, a[ky][kx + 1],     s01);
                        s10 = fmaf(w, a[ky + 1][kx],     s10);
                        s11 = fmaf(w, a[ky + 1][kx + 1], s11);
                    }
                float v = fmaxf(fmaxf(s00, s01), fmaxf(s10, s11));
                v = fmaxf(v, 0.f);
                // write one f16 half of the ic-pair element (byte store, no race)
                _Float16* ph = (_Float16*)&p1h[(c >> 1) * P1_CS + (py + 1) * P1_RS + (px + 1)];
                ph[c & 1] = (_Float16)v;
            }
        }
    }
    __syncthreads();

    // ---------------- phase 2: conv2 (1D winograd-x, f16 dot2) + pool -> p2 --
    // wave = oc-group of 8 (uniform -> packed weights via scalar cache),
    // lane = pooled pixel (49 of 64). macc accumulates fp32 via v_dot2_f32_f16
    // over ic-pairs; inverse winograd transform + pool at the end.
    {
        int wv = __builtin_amdgcn_readfirstlane(t >> 6);  // 0..3
        int oc0 = wv * 8;
        int lane = t & 63;
        if (lane < 49) {
            int py = lane / 7, px = lane - py * 7;
            float macc[2][4][8];
            #pragma unroll
            for (int yy = 0; yy < 2; ++yy)
                #pragma unroll
                for (int j = 0; j < 4; ++j)
                    #pragma unroll
                    for (int o = 0; o < 8; ++o) macc[yy][j][o] = 0.f;
            int ybase = py * 2, xbase = px * 2;           // padded coords, even
            for (int icp = 0; icp < 8; ++icp) {
                const unsigned* pch = &p1h[icp * P1_CS + ybase * P1_RS + xbase];
                half2v d2[4][4];
                #pragma unroll
                for (int r = 0; r < 4; ++r) {
                    uint2 q0 = *(const uint2*)(pch + r * P1_RS);
                    uint2 q1 = *(const uint2*)(pch + r * P1_RS + 2);
                    d2[r][0] = __builtin_bit_cast(half2v, q0.x);
                    d2[r][1] = __builtin_bit_cast(half2v, q0.y);
                    d2[r][2] = __builtin_bit_cast(half2v, q1.x);
                    d2[r][3] = __builtin_bit_cast(half2v, q1.y);
                }
                half2v v2[4][4];                          // B^T d (packed pk_add)
                #pragma unroll
                for (int r = 0; r < 4; ++r) {
                    v2[r][0] = d2[r][0] - d2[r][2];
                    v2[r][1] = d2[r][1] + d2[r][2];
                    v2[r][2] = d2[r][2] - d2[r][1];
                    v2[r][3] = d2[r][1] - d2[r][3];
                }
                const float* up = wsc + (size_t)((icp * 4 + wv) * 12) * 8;  // uniform
                #pragma unroll
                for (int o = 0; o < 8; ++o)
                    #pragma unroll
                    for (int ky = 0; ky < 3; ++ky)
                        #pragma unroll
                        for (int j = 0; j < 4; ++j) {
                            half2v u = __builtin_bit_cast(half2v, up[(ky * 4 + j) * 8 + o]);
                            macc[0][j][o] = __builtin_amdgcn_fdot2(u, v2[ky][j],     macc[0][j][o], false);
                            macc[1][j][o] = __builtin_amdgcn_fdot2(u, v2[ky + 1][j], macc[1][j][o], false);
                        }
            }
            #pragma unroll
            for (int o = 0; o < 8; ++o) {                 // inverse: A^T m
                float o00 = macc[0][0][o] + macc[0][1][o] + macc[0][2][o];
                float o01 = macc[0][1][o] - macc[0][2][o] - macc[0][3][o];
                float o10 = macc[1][0][o] + macc[1][1][o] + macc[1][2][o];
                float o11 = macc[1][1][o] - macc[1][2][o] - macc[1][3][o];
                float m4 = fmaxf(fmaxf(o00, o01), fmaxf(o10, o11)) + b2g[oc0 + o];
                p2[(oc0 + o) * 49 + lane] = fmaxf(m4, 0.f);
            }
        }
    }
    __syncthreads();

    // ---------------- phase 3: dense (1568 -> 4), one output per wave --------
    {
        int w = t >> 6, lane = t & 63;
        const float* dw = dwg + w * 1568;
        float partial = 0.f;
        for (int i = lane; i < 1568; i += 64)
            partial = fmaf(p2[i], dw[i], partial);
        #pragma unroll
        for (int m = 32; m >= 1; m >>= 1)
            partial += __shfl_xor(partial, m, 64);
        if (lane == 0) ang[w] = partial + dbg[w];
    }
    __syncthreads();

    // ---------------- phase 4: 4-qubit statevector (wave 0) ----------------
    if (t < 64) {
        int l = t & 15;
        float re = (l == 0) ? 1.f : 0.f;
        float im = 0.f;
        #pragma unroll
        for (int w = 0; w < 4; ++w) {        // initial RY(angle * pi)
            float th = ang[w] * (PI_F * 0.5f);
            float c = cosf(th), s = sinf(th);
            gate1(re, im, l, w, C2{c, 0.f}, C2{-s, 0.f}, C2{s, 0.f}, C2{c, 0.f});
        }
        #pragma unroll
        for (int layer = 0; layer < 2; ++layer) {
            #pragma unroll
            for (int q = 0; q < 4; ++q) {    // precomputed rot gates (uniform)
                const float* gm = wsc + WS_GROT + (layer * 4 + q) * 8;
                gate1(re, im, l, q, C2{gm[0], gm[1]}, C2{gm[2], gm[3]},
                                     C2{gm[4], gm[5]}, C2{gm[6], gm[7]});
            }
            const int pi_[6] = {0, 0, 0, 1, 1, 2};
            const int pj_[6] = {1, 2, 3, 2, 3, 3};
            #pragma unroll
            for (int k = 0; k < 6; ++k) {    // CNOT(i->j) then RZ on j
                int i = pi_[k], j = pj_[k];
                const float* em = wsc + WS_GENT + (layer * 6 + k) * 2;
                float ce = em[0], se = em[1];
                int maskj = 1 << (3 - j);
                float pre = __shfl_xor(re, maskj, 64);
                float pim = __shfl_xor(im, maskj, 64);
                bool bi = ((l >> (3 - i)) & 1) != 0;
                re = bi ? pre : re;
                im = bi ? pim : im;
                bool bj = (l & maskj) != 0;
                C2 ph{ce, bj ? se : -se};
                C2 r = cmul(C2{re, im}, ph);
                re = r.x; im = r.y;
            }
        }
        float pr = re * re + im * im;
        float z0 = ((l >> 3) & 1) ? -pr : pr;
        float z1 = ((l >> 2) & 1) ? -pr : pr;
        float z2 = ((l >> 1) & 1) ? -pr : pr;
        float z3 = (l & 1)        ? -pr : pr;
        #pragma unroll
        for (int m = 1; m <= 8; m <<= 1) {
            z0 += __shfl_xor(z0, m, 64);
            z1 += __shfl_xor(z1, m, 64);
            z2 += __shfl_xor(z2, m, 64);
            z3 += __shfl_xor(z3, m, 64);
        }
        if (t == 0) { zsh[0] = z0; zsh[1] = z1; zsh[2] = z2; zsh[3] = z3; }
    }
    __syncthreads();

    // ---------------- phase 5: post linear (4 -> 10) ----------------
    if (t < 10) {
        float o = pbg[t];
        #pragma unroll
        for (int w = 0; w < 4; ++w)
            o = fmaf(zsh[w], pwg[t * 4 + w], o);
        out[(size_t)b * 10 + t] = o;
    }
}

extern "C" void kernel_launch(void* const* d_in, const int* in_sizes, int n_in,
                              void* d_out, int out_size, void* d_ws, size_t ws_size,
                              hipStream_t stream) {
    const float* x  = (const float*)d_in[0];
    const float* w1 = (const float*)d_in[1];
    const float* b1 = (const float*)d_in[2];
    const float* w2 = (const float*)d_in[3];
    const float* b2 = (const float*)d_in[4];
    const float* dw = (const float*)d_in[5];
    const float* db = (const float*)d_in[6];
    const float* qp = (const float*)d_in[7];
    const float* pw = (const float*)d_in[8];
    const float* pb = (const float*)d_in[9];
    float* out = (float*)d_out;
    float* ws  = (float*)d_ws;
    int B = in_sizes[0] / 784;   // 4096

    qnn_prep<<<1, 256, 0, stream>>>(w2, qp, ws);
    qnn_fused<<<B, 256, 0, stream>>>(x, w1, b1, b2, dw, db, ws, pw, pb, out);
}

// Round 5
// 161.685 us; speedup vs baseline: 1.6618x; 1.0302x over previous
//
#include <hip/hip_runtime.h>

#define PI_F 3.14159265358979323846f

typedef _Float16 half2v __attribute__((ext_vector_type(2)));

struct C2 { float x, y; };
__device__ __forceinline__ C2 cmul(C2 a, C2 b) {
    return C2{a.x * b.x - a.y * b.y, a.x * b.y + a.y * b.x};
}

// Apply 2x2 complex gate M on wire w; one amplitude per lane (l = basis index,
// wire w is bit (3-w) of l).
__device__ __forceinline__ void gate1(float& re, float& im, int l, int w,
                                      C2 m00, C2 m01, C2 m10, C2 m11) {
    int mask = 1 << (3 - w);
    float pre = __shfl_xor(re, mask, 64);
    float pim = __shfl_xor(im, mask, 64);
    bool b = (l & mask) != 0;
    C2 d = b ? m11 : m00;
    C2 o = b ? m10 : m01;
    float nre = d.x * re - d.y * im + o.x * pre - o.y * pim;
    float nim = d.x * im + d.y * re + o.x * pim + o.y * pre;
    re = nre; im = nim;
}

// p1h layout: [icp][16 rows][20 cols] of uint = half2 {ic=2*icp, ic=2*icp+1}.
#define P1_RS 20
#define P1_CS (16 * P1_RS)   // 320

// ws layout (floats):
//   [0 .. 3071]   U2: winograd-1D transformed conv2 weights, f16-pair packed:
//                 idx = ((icp*4 + ocg)*12 + ky*4 + j)*8 + (oc&7),
//                 value bits = half2{u(ic=2icp), u(ic=2icp+1)}
//   [6144..6207]  rot gates: (layer*4+q)*8 + {m00,m01,m10,m11 as re,im pairs}
//   [6208..6231]  ent gates: (layer*6+k)*2 + {cos(e/2), sin(e/2)}
#define WS_GROT 6144
#define WS_GENT 6208

// ---------------- prologue: batch-invariant precompute ----------------
__global__ __launch_bounds__(256) void qnn_prep(
    const float* __restrict__ w2g, const float* __restrict__ qpg,
    float* __restrict__ ws)
{
    int t = threadIdx.x;
    // conv2 weight 1D-winograd transform (along x), packed by ic-pair.
    if (t < 256) {
        int icp = t >> 5, oc = t & 31;
        int ocg = oc >> 3, o = oc & 7;
        const float* ga = w2g + oc * 144 + (2 * icp) * 9;
        const float* gb = ga + 9;
        float* u = ws + (size_t)((icp * 4 + ocg) * 12) * 8 + o;
        #pragma unroll
        for (int ky = 0; ky < 3; ++ky) {
            float a0 = ga[ky * 3], a1 = ga[ky * 3 + 1], a2 = ga[ky * 3 + 2];
            float b0 = gb[ky * 3], b1 = gb[ky * 3 + 1], b2 = gb[ky * 3 + 2];
            float ua[4] = {a0, 0.5f * (a0 + a1 + a2), 0.5f * (a0 - a1 + a2), a2};
            float ub[4] = {b0, 0.5f * (b0 + b1 + b2), 0.5f * (b0 - b1 + b2), b2};
            #pragma unroll
            for (int j = 0; j < 4; ++j) {
                half2v h;
                h.x = (_Float16)ua[j];
                h.y = (_Float16)ub[j];
                u[(ky * 4 + j) * 8] = __builtin_bit_cast(float, h);
            }
        }
    }
    if (t < 8) {                     // rot gate matrices: M = RZ(a2) RY(a1) RX(a0)
        int layer = t >> 2, q = t & 3;
        int st = layer * 18;
        float a0 = qpg[st + 3 * q], a1 = qpg[st + 3 * q + 1], a2 = qpg[st + 3 * q + 2];
        float cx = cosf(0.5f * a0), sx = sinf(0.5f * a0);
        float cy = cosf(0.5f * a1), sy = sinf(0.5f * a1);
        float cz = cosf(0.5f * a2), sz = sinf(0.5f * a2);
        C2 T00{cy * cx,  sy * sx}, T01{-sy * cx, -cy * sx};
        C2 T10{sy * cx, -cy * sx}, T11{ cy * cx, -sy * sx};
        C2 E0{cz, -sz}, E1{cz, sz};
        C2 m00 = cmul(E0, T00), m01 = cmul(E0, T01);
        C2 m10 = cmul(E1, T10), m11 = cmul(E1, T11);
        float* gm = ws + WS_GROT + t * 8;
        gm[0] = m00.x; gm[1] = m00.y; gm[2] = m01.x; gm[3] = m01.y;
        gm[4] = m10.x; gm[5] = m10.y; gm[6] = m11.x; gm[7] = m11.y;
    }
    if (t >= 32 && t < 44) {         // entangler RZ phases
        int k = t - 32;
        float e = qpg[(k / 6) * 18 + 12 + (k % 6)];
        ws[WS_GENT + k * 2]     = cosf(0.5f * e);
        ws[WS_GENT + k * 2 + 1] = sinf(0.5f * e);
    }
}

__global__ __launch_bounds__(256, 5) void qnn_fused(
    const float* __restrict__ xg,
    const float* __restrict__ w1g, const float* __restrict__ b1g,
    const float* __restrict__ b2g,
    const float* __restrict__ dwg, const float* __restrict__ dbg,
    const float* __restrict__ wsc,      // precomputed U2 + gates
    const float* __restrict__ pwg, const float* __restrict__ pbg,
    float* __restrict__ out)
{
    const int b = blockIdx.x;
    const int t = threadIdx.x;

    __shared__ __align__(16) float xpad[30 * 30];         // x padded (zero border)
    __shared__ float w1s[16 * 9];
    __shared__ float b1s[16];
    __shared__ __align__(16) unsigned p1h[8 * P1_CS];     // 10240 B, half2 per elem
    __shared__ __align__(16) float p2[1568];              // (oc*49 + py*7 + px)
    __shared__ float ang[4];
    __shared__ float zsh[4];

    // ---------------- phase 0: stage into LDS ----------------
    const float* xb = xg + (size_t)b * 784;
    for (int j = t; j < 900; j += 256) {
        int y = j / 30, x = j - y * 30;
        float v = 0.f;
        if (y >= 1 && y <= 28 && x >= 1 && x <= 28)
            v = xb[(y - 1) * 28 + (x - 1)];
        xpad[j] = v;
    }
    if (t < 144) w1s[t] = w1g[t];
    if (t < 16)  b1s[t] = b1g[t];
    {   // zero p1h (incl. borders): 2560 uints = 640 uint4
        uint4 z4 = {0u, 0u, 0u, 0u};
        uint4* p4 = (uint4*)p1h;
        #pragma unroll
        for (int j = 0; j < 3; ++j) {
            int i = t + j * 256;
            if (i < 640) p4[i] = z4;
        }
    }
    __syncthreads();

    // ---------------- phase 1: conv1 + relu + 2x2 maxpool -> p1h (f16) -------
    {
        int c = t >> 4, s = t & 15;         // 16 threads per channel
        float wt[9];
        #pragma unroll
        for (int k = 0; k < 9; ++k) wt[k] = w1s[c * 9 + k];
        float bias = b1s[c];
        for (int pp = 0; pp < 13; ++pp) {   // 196 pooled pixels / 16
            int p = s + (pp << 4);
            if (p < 196) {
                int py = p / 14, px = p - py * 14;
                int y0 = py * 2, x0 = px * 2;   // even -> float2 aligned
                float a[4][4];
                #pragma unroll
                for (int r = 0; r < 4; ++r) {
                    float2 v0 = *(const float2*)&xpad[(y0 + r) * 30 + x0];
                    float2 v1 = *(const float2*)&xpad[(y0 + r) * 30 + x0 + 2];
                    a[r][0] = v0.x; a[r][1] = v0.y; a[r][2] = v1.x; a[r][3] = v1.y;
                }
                float s00 = bias, s01 = bias, s10 = bias, s11 = bias;
                #pragma unroll
                for (int ky = 0; ky < 3; ++ky)
                    #pragma unroll
                    for (int kx = 0; kx < 3; ++kx) {
                        float w = wt[ky * 3 + kx];
                        s00 = fmaf(w, a[ky][kx],         s00);
                        s01 = fmaf(w, a[ky][kx + 1],     s01);
                        s10 = fmaf(w, a[ky + 1][kx],     s10);
                        s11 = fmaf(w, a[ky + 1][kx + 1], s11);
                    }
                float v = fmaxf(fmaxf(s00, s01), fmaxf(s10, s11));
                v = fmaxf(v, 0.f);
                // write one f16 half of the ic-pair element (byte store, no race)
                _Float16* ph = (_Float16*)&p1h[(c >> 1) * P1_CS + (py + 1) * P1_RS + (px + 1)];
                ph[c & 1] = (_Float16)v;
            }
        }
    }
    __syncthreads();

    // ---------------- phase 2: conv2 (1D winograd-x, f16 dot2) + pool -> p2 --
    // wave = oc-group of 8 (uniform -> packed weights via scalar cache),
    // lane = pooled pixel (49 of 64). Row-streamed: transform input row r,
    // immediately accumulate into macc[0] (ky=r) and macc[1] (ky=r-1).
    // Keeps live set ~85 VGPR (macc 64 + one v-row) -> no spill at (256,5).
    {
        int wv = __builtin_amdgcn_readfirstlane(t >> 6);  // 0..3
        int oc0 = wv * 8;
        int lane = t & 63;
        if (lane < 49) {
            int py = lane / 7, px = lane - py * 7;
            float macc[2][4][8];
            #pragma unroll
            for (int yy = 0; yy < 2; ++yy)
                #pragma unroll
                for (int j = 0; j < 4; ++j)
                    #pragma unroll
                    for (int o = 0; o < 8; ++o) macc[yy][j][o] = 0.f;
            int ybase = py * 2, xbase = px * 2;           // padded coords, even
            for (int icp = 0; icp < 8; ++icp) {
                const unsigned* pch = &p1h[icp * P1_CS + ybase * P1_RS + xbase];
                const float* up = wsc + (size_t)((icp * 4 + wv) * 12) * 8;  // uniform
                #pragma unroll
                for (int r = 0; r < 4; ++r) {
                    uint2 q0 = *(const uint2*)(pch + r * P1_RS);
                    uint2 q1 = *(const uint2*)(pch + r * P1_RS + 2);
                    half2v d0 = __builtin_bit_cast(half2v, q0.x);
                    half2v d1 = __builtin_bit_cast(half2v, q0.y);
                    half2v dd2 = __builtin_bit_cast(half2v, q1.x);
                    half2v d3 = __builtin_bit_cast(half2v, q1.y);
                    half2v vr[4];                          // B^T d for this row
                    vr[0] = d0 - dd2;
                    vr[1] = d1 + dd2;
                    vr[2] = dd2 - d1;
                    vr[3] = d1 - d3;
                    if (r < 3) {                           // ky = r -> macc[0]
                        #pragma unroll
                        for (int o = 0; o < 8; ++o)
                            #pragma unroll
                            for (int j = 0; j < 4; ++j) {
                                half2v u = __builtin_bit_cast(half2v, up[(r * 4 + j) * 8 + o]);
                                macc[0][j][o] = __builtin_amdgcn_fdot2(u, vr[j], macc[0][j][o], false);
                            }
                    }
                    if (r > 0) {                           // ky = r-1 -> macc[1]
                        #pragma unroll
                        for (int o = 0; o < 8; ++o)
                            #pragma unroll
                            for (int j = 0; j < 4; ++j) {
                                half2v u = __builtin_bit_cast(half2v, up[((r - 1) * 4 + j) * 8 + o]);
                                macc[1][j][o] = __builtin_amdgcn_fdot2(u, vr[j], macc[1][j][o], false);
                            }
                    }
                }
            }
            #pragma unroll
            for (int o = 0; o < 8; ++o) {                 // inverse: A^T m
                float o00 = macc[0][0][o] + macc[0][1][o] + macc[0][2][o];
                float o01 = macc[0][1][o] - macc[0][2][o] - macc[0][3][o];
                float o10 = macc[1][0][o] + macc[1][1][o] + macc[1][2][o];
                float o11 = macc[1][1][o] - macc[1][2][o] - macc[1][3][o];
                float m4 = fmaxf(fmaxf(o00, o01), fmaxf(o10, o11)) + b2g[oc0 + o];
                p2[(oc0 + o) * 49 + lane] = fmaxf(m4, 0.f);
            }
        }
    }
    __syncthreads();

    // ---------------- phase 3: dense (1568 -> 4), one output per wave --------
    {
        int w = t >> 6, lane = t & 63;
        const float* dw = dwg + w * 1568;
        float partial = 0.f;
        for (int i = lane; i < 1568; i += 64)
            partial = fmaf(p2[i], dw[i], partial);
        #pragma unroll
        for (int m = 32; m >= 1; m >>= 1)
            partial += __shfl_xor(partial, m, 64);
        if (lane == 0) ang[w] = partial + dbg[w];
    }
    __syncthreads();

    // ---------------- phase 4: 4-qubit statevector (wave 0) ----------------
    if (t < 64) {
        int l = t & 15;
        float re = (l == 0) ? 1.f : 0.f;
        float im = 0.f;
        #pragma unroll
        for (int w = 0; w < 4; ++w) {        // initial RY(angle * pi)
            float th = ang[w] * (PI_F * 0.5f);
            float c = cosf(th), s = sinf(th);
            gate1(re, im, l, w, C2{c, 0.f}, C2{-s, 0.f}, C2{s, 0.f}, C2{c, 0.f});
        }
        #pragma unroll
        for (int layer = 0; layer < 2; ++layer) {
            #pragma unroll
            for (int q = 0; q < 4; ++q) {    // precomputed rot gates (uniform)
                const float* gm = wsc + WS_GROT + (layer * 4 + q) * 8;
                gate1(re, im, l, q, C2{gm[0], gm[1]}, C2{gm[2], gm[3]},
                                     C2{gm[4], gm[5]}, C2{gm[6], gm[7]});
            }
            const int pi_[6] = {0, 0, 0, 1, 1, 2};
            const int pj_[6] = {1, 2, 3, 2, 3, 3};
            #pragma unroll
            for (int k = 0; k < 6; ++k) {    // CNOT(i->j) then RZ on j
                int i = pi_[k], j = pj_[k];
                const float* em = wsc + WS_GENT + (layer * 6 + k) * 2;
                float ce = em[0], se = em[1];
                int maskj = 1 << (3 - j);
                float pre = __shfl_xor(re, maskj, 64);
                float pim = __shfl_xor(im, maskj, 64);
                bool bi = ((l >> (3 - i)) & 1) != 0;
                re = bi ? pre : re;
                im = bi ? pim : im;
                bool bj = (l & maskj) != 0;
                C2 ph{ce, bj ? se : -se};
                C2 r = cmul(C2{re, im}, ph);
                re = r.x; im = r.y;
            }
        }
        float pr = re * re + im * im;
        float z0 = ((l >> 3) & 1) ? -pr : pr;
        float z1 = ((l >> 2) & 1) ? -pr : pr;
        float z2 = ((l >> 1) & 1) ? -pr : pr;
        float z3 = (l & 1)        ? -pr : pr;
        #pragma unroll
        for (int m = 1; m <= 8; m <<= 1) {
            z0 += __shfl_xor(z0, m, 64);
            z1 += __shfl_xor(z1, m, 64);
            z2 += __shfl_xor(z2, m, 64);
            z3 += __shfl_xor(z3, m, 64);
        }
        if (t == 0) { zsh[0] = z0; zsh[1] = z1; zsh[2] = z2; zsh[3] = z3; }
    }
    __syncthreads();

    // ---------------- phase 5: post linear (4 -> 10) ----------------
    if (t < 10) {
        float o = pbg[t];
        #pragma unroll
        for (int w = 0; w < 4; ++w)
            o = fmaf(zsh[w], pwg[t * 4 + w], o);
        out[(size_t)b * 10 + t] = o;
    }
}

extern "C" void kernel_launch(void* const* d_in, const int* in_sizes, int n_in,
                              void* d_out, int out_size, void* d_ws, size_t ws_size,
                              hipStream_t stream) {
    const float* x  = (const float*)d_in[0];
    const float* w1 = (const float*)d_in[1];
    const float* b1 = (const float*)d_in[2];
    const float* w2 = (const float*)d_in[3];
    const float* b2 = (const float*)d_in[4];
    const float* dw = (const float*)d_in[5];
    const float* db = (const float*)d_in[6];
    const float* qp = (const float*)d_in[7];
    const float* pw = (const float*)d_in[8];
    const float* pb = (const float*)d_in[9];
    float* out = (float*)d_out;
    float* ws  = (float*)d_ws;
    int B = in_sizes[0] / 784;   // 4096

    qnn_prep<<<1, 256, 0, stream>>>(w2, qp, ws);
    qnn_fused<<<B, 256, 0, stream>>>(x, w1, b1, b2, dw, db, ws, pw, pb, out);
}

// Round 7
// 130.039 us; speedup vs baseline: 2.0663x; 1.2434x over previous
//
#include <hip/hip_runtime.h>

#define PI_F 3.14159265358979323846f

typedef _Float16 half2v __attribute__((ext_vector_type(2)));
typedef _Float16 half4v __attribute__((ext_vector_type(4)));
typedef _Float16 half8v __attribute__((ext_vector_type(8)));
typedef float f32x4 __attribute__((ext_vector_type(4)));

struct C2 { float x, y; };
__device__ __forceinline__ C2 cmul(C2 a, C2 b) {
    return C2{a.x * b.x - a.y * b.y, a.x * b.y + a.y * b.x};
}

__device__ __forceinline__ void gate1(float& re, float& im, int l, int w,
                                      C2 m00, C2 m01, C2 m10, C2 m11) {
    int mask = 1 << (3 - w);
    float pre = __shfl_xor(re, mask, 64);
    float pim = __shfl_xor(im, mask, 64);
    bool b = (l & mask) != 0;
    C2 d = b ? m11 : m00;
    C2 o = b ? m10 : m01;
    float nre = d.x * re - d.y * im + o.x * pre - o.y * pim;
    float nim = d.x * im + d.y * re + o.x * pim + o.y * pre;
    re = nre; im = nim;
}

// ws layout (floats):
//   [0..2559]    conv2 B-frags: [(kstep*2+ntile)*64 + lane] * 4dw, half8 each
//                B[k=kq*8+jj][oc=ntile*16+(lane&15)], k-order: pi*16+ic,
//                pi=(ky*3+kx) 0..8 (pi=9 pad -> 0), ic 0..15
//   [2560..2687] conv1 B-frags: [lane]*2dw, half4: B[k=kq*4+j][oc=lane&15],
//                k-order ky*4+kx (ky=kq, kx=j; zero if ky>2 or kx>2)
//   [2688..2751] rot gates: (layer*4+q)*8 floats
//   [2752..2775] ent gates: (layer*6+k)*2 floats
#define WS_C1B 2560
#define WS_GROT 2688
#define WS_GENT 2752

// ---------------- prologue: batch-invariant precompute ----------------
__global__ __launch_bounds__(256) void qnn_prep(
    const float* __restrict__ w1g, const float* __restrict__ w2g,
    const float* __restrict__ qpg, float* __restrict__ ws)
{
    int t = threadIdx.x;
    // conv2 B-fragments
    for (int e = t; e < 640; e += 256) {
        int kstep = e >> 7, rem = e & 127;
        int ntile = rem >> 6, lane = rem & 63;
        int kq = lane >> 4, n = lane & 15;
        int oc = ntile * 16 + n;
        int pi = kstep * 2 + (kq >> 1);
        half8v h;
        #pragma unroll
        for (int jj = 0; jj < 8; ++jj) {
            int ic = (kq & 1) * 8 + jj;
            float v = (pi < 9) ? w2g[oc * 144 + ic * 9 + pi] : 0.f;
            h[jj] = (_Float16)v;
        }
        *(float4*)(ws + e * 4) = __builtin_bit_cast(float4, h);
    }
    // conv1 B-fragments
    if (t < 64) {
        int ky = t >> 4, n = t & 15;
        half4v h;
        #pragma unroll
        for (int j = 0; j < 4; ++j) {
            float v = (ky < 3 && j < 3) ? w1g[n * 9 + ky * 3 + j] : 0.f;
            h[j] = (_Float16)v;
        }
        *(float2*)(ws + WS_C1B + t * 2) = __builtin_bit_cast(float2, h);
    }
    if (t < 8) {                     // rot gate matrices: M = RZ(a2) RY(a1) RX(a0)
        int layer = t >> 2, q = t & 3;
        int st = layer * 18;
        float a0 = qpg[st + 3 * q], a1 = qpg[st + 3 * q + 1], a2 = qpg[st + 3 * q + 2];
        float cx = cosf(0.5f * a0), sx = sinf(0.5f * a0);
        float cy = cosf(0.5f * a1), sy = sinf(0.5f * a1);
        float cz = cosf(0.5f * a2), sz = sinf(0.5f * a2);
        C2 T00{cy * cx,  sy * sx}, T01{-sy * cx, -cy * sx};
        C2 T10{sy * cx, -cy * sx}, T11{ cy * cx, -sy * sx};
        C2 E0{cz, -sz}, E1{cz, sz};
        C2 m00 = cmul(E0, T00), m01 = cmul(E0, T01);
        C2 m10 = cmul(E1, T10), m11 = cmul(E1, T11);
        float* gm = ws + WS_GROT + t * 8;
        gm[0] = m00.x; gm[1] = m00.y; gm[2] = m01.x; gm[3] = m01.y;
        gm[4] = m10.x; gm[5] = m10.y; gm[6] = m11.x; gm[7] = m11.y;
    }
    if (t >= 32 && t < 44) {         // entangler RZ phases
        int k = t - 32;
        float e = qpg[(k / 6) * 18 + 12 + (k % 6)];
        ws[WS_GENT + k * 2]     = cosf(0.5f * e);
        ws[WS_GENT + k * 2 + 1] = sinf(0.5f * e);
    }
}

__global__ __launch_bounds__(256, 5) void qnn_fused(
    const float* __restrict__ xg,
    const float* __restrict__ b1g, const float* __restrict__ b2g,
    const float* __restrict__ dwg, const float* __restrict__ dbg,
    const float* __restrict__ wsc,
    const float* __restrict__ pwg, const float* __restrict__ pbg,
    float* __restrict__ out)
{
    const int b = blockIdx.x;
    const int t = threadIdx.x;
    const int lane = t & 63;
    const int wv = __builtin_amdgcn_readfirstlane(t >> 6);
    const int kq = lane >> 4;        // operand k-quad == C/D row-quad
    const int lm = lane & 15;

    // xhl: padded 30x30 input as half2{hi,lo} (fp32 split); +30 pad tail for
    // the kx=3 zero-weight column overrun.
    __shared__ __align__(16) unsigned xhl[930];
    // p1f: conv1 pooled out, f16, [row 0..15][col 0..19][ic 0..15], zero borders
    __shared__ __align__(16) _Float16 p1f[16 * 20 * 16];
    __shared__ __align__(16) float p2[1568];              // (oc*49 + quad)
    __shared__ float ang[4];
    __shared__ float zsh[4];

    // ---- preload B-fragments (global, L2-hot; latency hidden by phases 0-1)
    half8v bC2[5][2];
    {
        const float4* wsB = (const float4*)wsc;
        #pragma unroll
        for (int ks = 0; ks < 5; ++ks)
            #pragma unroll
            for (int nt = 0; nt < 2; ++nt)
                bC2[ks][nt] = __builtin_bit_cast(half8v, wsB[(ks * 2 + nt) * 64 + lane]);
    }
    half4v bC1 = __builtin_bit_cast(half4v, *(const float2*)(wsc + WS_C1B + lane * 2));
    float bias1 = b1g[lm];
    float b20 = b2g[lm], b21 = b2g[16 + lm];

    // ---------------- phase 0: stage x (hi/lo f16 split) + zero p1f ----------
    const float* xb = xg + (size_t)b * 784;
    for (int j = t; j < 900; j += 256) {
        int y = j / 30, x = j - y * 30;
        float v = 0.f;
        if (y >= 1 && y <= 28 && x >= 1 && x <= 28)
            v = xb[(y - 1) * 28 + (x - 1)];
        _Float16 h = (_Float16)v;
        _Float16 l = (_Float16)(v - (float)h);
        half2v p; p.x = h; p.y = l;
        xhl[j] = __builtin_bit_cast(unsigned, p);
    }
    if (t < 30) xhl[900 + t] = 0u;
    {   // zero p1f: 10240 B = 640 uint4
        uint4 z4 = {0u, 0u, 0u, 0u};
        uint4* p4 = (uint4*)p1f;
        #pragma unroll
        for (int j = 0; j < 3; ++j) {
            int i = t + j * 256;
            if (i < 640) p4[i] = z4;
        }
    }
    __syncthreads();

    // ---------------- phase 1: conv1 via MFMA 16x16x16 (hi+lo) --------------
    // M=784 pre-pool pixels, ordered m=4*p14+pos -> lane's 4 C-regs = one pool
    // window. K=16 (ky*4+kx, zero-padded), N=16 oc. 49 m-tiles over 4 waves.
    {
        int kyc = (kq < 3) ? kq : 0;   // kq==3 rows have zero weights
        for (int tile = wv; tile < 49; tile += 4) {
            int m = tile * 16 + lm;
            int p14 = m >> 2, pos = m & 3;
            int Y = p14 / 14, X = p14 - Y * 14;
            int py = 2 * Y + (pos >> 1), px = 2 * X + (pos & 1);
            int base = (py + kyc) * 30 + px;
            unsigned u0 = xhl[base], u1 = xhl[base + 1], u2 = xhl[base + 2], u3 = xhl[base + 3];
            half2v h0 = __builtin_bit_cast(half2v, u0);
            half2v h1 = __builtin_bit_cast(half2v, u1);
            half2v h2 = __builtin_bit_cast(half2v, u2);
            half2v h3 = __builtin_bit_cast(half2v, u3);
            half4v ah = {h0.x, h1.x, h2.x, h3.x};
            half4v al = {h0.y, h1.y, h2.y, h3.y};
            f32x4 acc = {bias1, bias1, bias1, bias1};
            acc = __builtin_amdgcn_mfma_f32_16x16x16f16(ah, bC1, acc, 0, 0, 0);
            acc = __builtin_amdgcn_mfma_f32_16x16x16f16(al, bC1, acc, 0, 0, 0);
            // pool + relu; this lane owns pooled pixel tile*4 + kq, channel lm
            float v = fmaxf(fmaxf(acc.x, acc.y), fmaxf(acc.z, acc.w));
            v = fmaxf(v, 0.f);
            int q14 = tile * 4 + kq;
            int r = q14 / 14, c = q14 - r * 14;
            p1f[((r + 1) * 20 + (c + 1)) * 16 + lm] = (_Float16)v;
        }
    }
    __syncthreads();

    // ---------------- phase 2: conv2 via MFMA 16x16x32 ----------------------
    // M=196 (pool-ordered, 13 tiles), N=32 (2 tiles), K=144->160 (5 steps).
    // k-order pi*16+ic -> A-frag = one ds_read_b128 (ic-contiguous).
    {
        for (int tile = wv; tile < 13; tile += 4) {
            int m = tile * 16 + lm;
            int quad = m >> 2; if (quad > 48) quad = 48;   // clamp pad rows
            int pos = m & 3;
            int Y = quad / 7, X = quad - Y * 7;
            int py = 2 * Y + (pos >> 1), px = 2 * X + (pos & 1);
            int base0 = py * 20 + px;
            f32x4 acc0 = {b20, b20, b20, b20};
            f32x4 acc1 = {b21, b21, b21, b21};
            int ich = (kq & 1) * 8;
            #pragma unroll
            for (int ks = 0; ks < 5; ++ks) {
                int pi = ks * 2 + (kq >> 1);
                if (pi > 8) pi = 8;                        // pad k -> zero B
                int ky = (pi >= 6) ? 2 : ((pi >= 3) ? 1 : 0);
                int kx = pi - ky * 3;
                half8v a = *(const half8v*)(&p1f[(base0 + ky * 20 + kx) * 16 + ich]);
                acc0 = __builtin_amdgcn_mfma_f32_16x16x32_f16(a, bC2[ks][0], acc0, 0, 0, 0);
                acc1 = __builtin_amdgcn_mfma_f32_16x16x32_f16(a, bC2[ks][1], acc1, 0, 0, 0);
            }
            int quadO = tile * 4 + kq;                     // pooled pixel owned
            if (quadO < 49) {
                float v0 = fmaxf(fmaxf(acc0.x, acc0.y), fmaxf(acc0.z, acc0.w));
                float v1 = fmaxf(fmaxf(acc1.x, acc1.y), fmaxf(acc1.z, acc1.w));
                p2[lm * 49 + quadO]        = fmaxf(v0, 0.f);
                p2[(16 + lm) * 49 + quadO] = fmaxf(v1, 0.f);
            }
        }
    }
    __syncthreads();

    // ---------------- phase 3: dense (1568 -> 4), one output per wave --------
    {
        int w = t >> 6;
        const float* dw = dwg + w * 1568;
        float partial = 0.f;
        for (int i = lane; i < 1568; i += 64)
            partial = fmaf(p2[i], dw[i], partial);
        #pragma unroll
        for (int m = 32; m >= 1; m >>= 1)
            partial += __shfl_xor(partial, m, 64);
        if (lane == 0) ang[w] = partial + dbg[w];
    }
    __syncthreads();

    // ---------------- phase 4: 4-qubit statevector (wave 0) ----------------
    if (t < 64) {
        int l = t & 15;
        float re = (l == 0) ? 1.f : 0.f;
        float im = 0.f;
        #pragma unroll
        for (int w = 0; w < 4; ++w) {        // initial RY(angle * pi)
            float th = ang[w] * (PI_F * 0.5f);
            float c = cosf(th), s = sinf(th);
            gate1(re, im, l, w, C2{c, 0.f}, C2{-s, 0.f}, C2{s, 0.f}, C2{c, 0.f});
        }
        #pragma unroll
        for (int layer = 0; layer < 2; ++layer) {
            #pragma unroll
            for (int q = 0; q < 4; ++q) {    // precomputed rot gates (uniform)
                const float* gm = wsc + WS_GROT + (layer * 4 + q) * 8;
                gate1(re, im, l, q, C2{gm[0], gm[1]}, C2{gm[2], gm[3]},
                                     C2{gm[4], gm[5]}, C2{gm[6], gm[7]});
            }
            const int pi_[6] = {0, 0, 0, 1, 1, 2};
            const int pj_[6] = {1, 2, 3, 2, 3, 3};
            #pragma unroll
            for (int k = 0; k < 6; ++k) {    // CNOT(i->j) then RZ on j
                int i = pi_[k], j = pj_[k];
                const float* em = wsc + WS_GENT + (layer * 6 + k) * 2;
                float ce = em[0], se = em[1];
                int maskj = 1 << (3 - j);
                float pre = __shfl_xor(re, maskj, 64);
                float pim = __shfl_xor(im, maskj, 64);
                bool bi = ((l >> (3 - i)) & 1) != 0;
                re = bi ? pre : re;
                im = bi ? pim : im;
                bool bj = (l & maskj) != 0;
                C2 ph{ce, bj ? se : -se};
                C2 r = cmul(C2{re, im}, ph);
                re = r.x; im = r.y;
            }
        }
        float pr = re * re + im * im;
        float z0 = ((l >> 3) & 1) ? -pr : pr;
        float z1 = ((l >> 2) & 1) ? -pr : pr;
        float z2 = ((l >> 1) & 1) ? -pr : pr;
        float z3 = (l & 1)        ? -pr : pr;
        #pragma unroll
        for (int m = 1; m <= 8; m <<= 1) {
            z0 += __shfl_xor(z0, m, 64);
            z1 += __shfl_xor(z1, m, 64);
            z2 += __shfl_xor(z2, m, 64);
            z3 += __shfl_xor(z3, m, 64);
        }
        if (t == 0) { zsh[0] = z0; zsh[1] = z1; zsh[2] = z2; zsh[3] = z3; }
    }
    __syncthreads();

    // ---------------- phase 5: post linear (4 -> 10) ----------------
    if (t < 10) {
        float o = pbg[t];
        #pragma unroll
        for (int w = 0; w < 4; ++w)
            o = fmaf(zsh[w], pwg[t * 4 + w], o);
        out[(size_t)b * 10 + t] = o;
    }
}

extern "C" void kernel_launch(void* const* d_in, const int* in_sizes, int n_in,
                              void* d_out, int out_size, void* d_ws, size_t ws_size,
                              hipStream_t stream) {
    const float* x  = (const float*)d_in[0];
    const float* w1 = (const float*)d_in[1];
    const float* b1 = (const float*)d_in[2];
    const float* w2 = (const float*)d_in[3];
    const float* b2 = (const float*)d_in[4];
    const float* dw = (const float*)d_in[5];
    const float* db = (const float*)d_in[6];
    const float* qp = (const float*)d_in[7];
    const float* pw = (const float*)d_in[8];
    const float* pb = (const float*)d_in[9];
    float* out = (float*)d_out;
    float* ws  = (float*)d_ws;
    int B = in_sizes[0] / 784;   // 4096

    qnn_prep<<<1, 256, 0, stream>>>(w1, w2, qp, ws);
    qnn_fused<<<B, 256, 0, stream>>>(x, b1, b2, dw, db, ws, pw, pb, out);
}

// Round 8
// 117.699 us; speedup vs baseline: 2.2829x; 1.1048x over previous
//
#include <hip/hip_runtime.h>

#define PI_F 3.14159265358979323846f

typedef _Float16 half2v __attribute__((ext_vector_type(2)));
typedef _Float16 half4v __attribute__((ext_vector_type(4)));
typedef _Float16 half8v __attribute__((ext_vector_type(8)));
typedef float f32x4 __attribute__((ext_vector_type(4)));

struct C2 { float x, y; };
__device__ __forceinline__ C2 cmul(C2 a, C2 b) {
    return C2{a.x * b.x - a.y * b.y, a.x * b.y + a.y * b.x};
}

__device__ __forceinline__ void gate1(float& re, float& im, int l, int w,
                                      C2 m00, C2 m01, C2 m10, C2 m11) {
    int mask = 1 << (3 - w);
    float pre = __shfl_xor(re, mask, 64);
    float pim = __shfl_xor(im, mask, 64);
    bool b = (l & mask) != 0;
    C2 d = b ? m11 : m00;
    C2 o = b ? m10 : m01;
    float nre = d.x * re - d.y * im + o.x * pre - o.y * pim;
    float nim = d.x * im + d.y * re + o.x * pim + o.y * pre;
    re = nre; im = nim;
}

// ws layout (floats):
//   [0..2559]    conv2 B-frags (half8 per lane per (kstep,ntile))
//   [2560..2687] conv1 B-frags (half4 per lane)
//   [2688..8959] dwT: dense_w transposed, float4 per (oc*49+pixel):
//                {dw[0][i], dw[1][i], dw[2][i], dw[3][i]}
//   [8960..9023] rot gates: (layer*4+q)*8 floats
//   [9024..9047] ent gates: (layer*6+k)*2 floats
#define WS_C1B 2560
#define WS_DWT 2688
#define WS_GROT 8960
#define WS_GENT 9024

// ---------------- prologue: batch-invariant precompute ----------------
__global__ __launch_bounds__(256) void qnn_prep(
    const float* __restrict__ w1g, const float* __restrict__ w2g,
    const float* __restrict__ dwg, const float* __restrict__ qpg,
    float* __restrict__ ws)
{
    int t = threadIdx.x;
    // conv2 B-fragments
    for (int e = t; e < 640; e += 256) {
        int kstep = e >> 7, rem = e & 127;
        int ntile = rem >> 6, lane = rem & 63;
        int kq = lane >> 4, n = lane & 15;
        int oc = ntile * 16 + n;
        int pi = kstep * 2 + (kq >> 1);
        half8v h;
        #pragma unroll
        for (int jj = 0; jj < 8; ++jj) {
            int ic = (kq & 1) * 8 + jj;
            float v = (pi < 9) ? w2g[oc * 144 + ic * 9 + pi] : 0.f;
            h[jj] = (_Float16)v;
        }
        *(float4*)(ws + e * 4) = __builtin_bit_cast(float4, h);
    }
    // conv1 B-fragments
    if (t < 64) {
        int ky = t >> 4, n = t & 15;
        half4v h;
        #pragma unroll
        for (int j = 0; j < 4; ++j) {
            float v = (ky < 3 && j < 3) ? w1g[n * 9 + ky * 3 + j] : 0.f;
            h[j] = (_Float16)v;
        }
        *(float2*)(ws + WS_C1B + t * 2) = __builtin_bit_cast(float2, h);
    }
    // dense_w transpose: float4 of the 4 rows per input element
    for (int e = t; e < 1568; e += 256) {
        float4 v = {dwg[e], dwg[1568 + e], dwg[3136 + e], dwg[4704 + e]};
        *(float4*)(ws + WS_DWT + e * 4) = v;
    }
    if (t < 8) {                     // rot gate matrices: M = RZ(a2) RY(a1) RX(a0)
        int layer = t >> 2, q = t & 3;
        int st = layer * 18;
        float a0 = qpg[st + 3 * q], a1 = qpg[st + 3 * q + 1], a2 = qpg[st + 3 * q + 2];
        float cx = cosf(0.5f * a0), sx = sinf(0.5f * a0);
        float cy = cosf(0.5f * a1), sy = sinf(0.5f * a1);
        float cz = cosf(0.5f * a2), sz = sinf(0.5f * a2);
        C2 T00{cy * cx,  sy * sx}, T01{-sy * cx, -cy * sx};
        C2 T10{sy * cx, -cy * sx}, T11{ cy * cx, -sy * sx};
        C2 E0{cz, -sz}, E1{cz, sz};
        C2 m00 = cmul(E0, T00), m01 = cmul(E0, T01);
        C2 m10 = cmul(E1, T10), m11 = cmul(E1, T11);
        float* gm = ws + WS_GROT + t * 8;
        gm[0] = m00.x; gm[1] = m00.y; gm[2] = m01.x; gm[3] = m01.y;
        gm[4] = m10.x; gm[5] = m10.y; gm[6] = m11.x; gm[7] = m11.y;
    }
    if (t >= 32 && t < 44) {         // entangler RZ phases
        int k = t - 32;
        float e = qpg[(k / 6) * 18 + 12 + (k % 6)];
        ws[WS_GENT + k * 2]     = cosf(0.5f * e);
        ws[WS_GENT + k * 2 + 1] = sinf(0.5f * e);
    }
}

__global__ __launch_bounds__(256, 6) void qnn_fused(
    const float* __restrict__ xg,
    const float* __restrict__ b1g, const float* __restrict__ b2g,
    const float* __restrict__ dbg,
    const float* __restrict__ wsc,
    const float* __restrict__ pwg, const float* __restrict__ pbg,
    float* __restrict__ out)
{
    const int b = blockIdx.x;
    const int t = threadIdx.x;
    const int lane = t & 63;
    const int wv = __builtin_amdgcn_readfirstlane(t >> 6);
    const int kq = lane >> 4;        // operand k-quad == C/D row-quad
    const int lm = lane & 15;

    // xhl: padded 30x30 input as half2{hi,lo} (fp32 split); +30 pad tail for
    // the kx=3 zero-weight column overrun.
    __shared__ __align__(16) unsigned xhl[930];
    // p1f: conv1 pooled out, f16, [row 0..15][col 0..19][ic 0..15], zero borders
    __shared__ __align__(16) _Float16 p1f[16 * 20 * 16];
    __shared__ __align__(16) float angp[16];              // per-wave dense partials

    // ---- preload B-fragments (global, L2-hot; latency hidden by phase 0-1)
    half8v bC2[5][2];
    {
        const float4* wsB = (const float4*)wsc;
        #pragma unroll
        for (int ks = 0; ks < 5; ++ks)
            #pragma unroll
            for (int nt = 0; nt < 2; ++nt)
                bC2[ks][nt] = __builtin_bit_cast(half8v, wsB[(ks * 2 + nt) * 64 + lane]);
    }
    half4v bC1 = __builtin_bit_cast(half4v, *(const float2*)(wsc + WS_C1B + lane * 2));
    float bias1 = b1g[lm];
    float b20 = b2g[lm], b21 = b2g[16 + lm];

    // ---------------- phase 0: stage x (hi/lo f16 split) + zero p1f ----------
    const float* xb = xg + (size_t)b * 784;
    for (int j = t; j < 900; j += 256) {
        int y = j / 30, x = j - y * 30;
        float v = 0.f;
        if (y >= 1 && y <= 28 && x >= 1 && x <= 28)
            v = xb[(y - 1) * 28 + (x - 1)];
        _Float16 h = (_Float16)v;
        _Float16 l = (_Float16)(v - (float)h);
        half2v p; p.x = h; p.y = l;
        xhl[j] = __builtin_bit_cast(unsigned, p);
    }
    if (t < 30) xhl[900 + t] = 0u;
    {   // zero p1f: 10240 B = 640 uint4
        uint4 z4 = {0u, 0u, 0u, 0u};
        uint4* p4 = (uint4*)p1f;
        #pragma unroll
        for (int j = 0; j < 3; ++j) {
            int i = t + j * 256;
            if (i < 640) p4[i] = z4;
        }
    }
    __syncthreads();

    // ---------------- phase 1: conv1 via MFMA 16x16x16 (hi+lo) --------------
    // M=784 pre-pool pixels (m=4*p14+pos), K=16 (ky*4+kx), N=16 oc.
    // Incremental /14 addressing (add-and-wrap instead of per-tile div).
    {
        int kyc = (kq < 3) ? kq : 0;   // kq==3 rows have zero weights
        int pos = lm & 3;
        int pyo = pos >> 1, pxo = pos & 1;
        int p14 = wv * 4 + (lm >> 2);
        int Y = p14 / 14, X = p14 - Y * 14;      // div once
        int q14 = wv * 4 + kq;
        int r = q14 / 14, c = q14 - r * 14;      // div once
        for (int tile = wv; tile < 49; tile += 4) {
            int py = 2 * Y + pyo, px = 2 * X + pxo;
            int base = (py + kyc) * 30 + px;
            unsigned u0 = xhl[base], u1 = xhl[base + 1], u2 = xhl[base + 2], u3 = xhl[base + 3];
            half2v h0 = __builtin_bit_cast(half2v, u0);
            half2v h1 = __builtin_bit_cast(half2v, u1);
            half2v h2 = __builtin_bit_cast(half2v, u2);
            half2v h3 = __builtin_bit_cast(half2v, u3);
            half4v ah = {h0.x, h1.x, h2.x, h3.x};
            half4v al = {h0.y, h1.y, h2.y, h3.y};
            f32x4 acc = {bias1, bias1, bias1, bias1};
            acc = __builtin_amdgcn_mfma_f32_16x16x16f16(ah, bC1, acc, 0, 0, 0);
            acc = __builtin_amdgcn_mfma_f32_16x16x16f16(al, bC1, acc, 0, 0, 0);
            float v = fmaxf(fmaxf(acc.x, acc.y), fmaxf(acc.z, acc.w));
            v = fmaxf(v, 0.f);
            p1f[((r + 1) * 20 + (c + 1)) * 16 + lm] = (_Float16)v;
            // p14 += 16, q14 += 16 (grid width 14): add-and-wrap
            X += 2; Y += 1; if (X >= 14) { X -= 14; Y += 1; }
            c += 2; r += 1; if (c >= 14) { c -= 14; r += 1; }
        }
    }
    __syncthreads();

    // ---------------- phase 2: conv2 via MFMA 16x16x32 + fused dense --------
    // M=196 (pool-ordered, 13 tiles), N=32 (2 tiles), K=144->160 (5 steps).
    // Epilogue: pool+relu in-register, then accumulate the 4 dense dots via
    // pre-transposed dwT (float4 per element, L2-hot) - no p2 materialization.
    {
        float dp0 = 0.f, dp1 = 0.f, dp2 = 0.f, dp3 = 0.f;
        const float4* dt = (const float4*)(wsc + WS_DWT);
        for (int tile = wv; tile < 13; tile += 4) {
            int m = tile * 16 + lm;
            int quad = m >> 2; if (quad > 48) quad = 48;   // clamp pad rows
            int pos = m & 3;
            int Y = quad / 7, X = quad - Y * 7;
            int py = 2 * Y + (pos >> 1), px = 2 * X + (pos & 1);
            int base0 = py * 20 + px;
            f32x4 acc0 = {b20, b20, b20, b20};
            f32x4 acc1 = {b21, b21, b21, b21};
            int ich = (kq & 1) * 8;
            #pragma unroll
            for (int ks = 0; ks < 5; ++ks) {
                int pi = ks * 2 + (kq >> 1);
                if (pi > 8) pi = 8;                        // pad k -> zero B
                int ky = (pi >= 6) ? 2 : ((pi >= 3) ? 1 : 0);
                int kx = pi - ky * 3;
                half8v a = *(const half8v*)(&p1f[(base0 + ky * 20 + kx) * 16 + ich]);
                acc0 = __builtin_amdgcn_mfma_f32_16x16x32_f16(a, bC2[ks][0], acc0, 0, 0, 0);
                acc1 = __builtin_amdgcn_mfma_f32_16x16x32_f16(a, bC2[ks][1], acc1, 0, 0, 0);
            }
            int quadO = tile * 4 + kq;                     // pooled pixel owned
            if (quadO < 49) {
                float v0 = fmaxf(fmaxf(fmaxf(acc0.x, acc0.y), fmaxf(acc0.z, acc0.w)), 0.f);
                float v1 = fmaxf(fmaxf(fmaxf(acc1.x, acc1.y), fmaxf(acc1.z, acc1.w)), 0.f);
                float4 q0 = dt[lm * 49 + quadO];
                float4 q1 = dt[(16 + lm) * 49 + quadO];
                dp0 = fmaf(v0, q0.x, fmaf(v1, q1.x, dp0));
                dp1 = fmaf(v0, q0.y, fmaf(v1, q1.y, dp1));
                dp2 = fmaf(v0, q0.z, fmaf(v1, q1.z, dp2));
                dp3 = fmaf(v0, q0.w, fmaf(v1, q1.w, dp3));
            }
        }
        #pragma unroll
        for (int m = 32; m >= 1; m >>= 1) {
            dp0 += __shfl_xor(dp0, m, 64);
            dp1 += __shfl_xor(dp1, m, 64);
            dp2 += __shfl_xor(dp2, m, 64);
            dp3 += __shfl_xor(dp3, m, 64);
        }
        if (lane == 0) {
            float4 dpv = {dp0, dp1, dp2, dp3};
            *(float4*)&angp[wv * 4] = dpv;
        }
    }
    __syncthreads();

    // ---------------- phase 3: quantum sim + post linear (wave 0 only) ------
    if (t < 64) {
        float4 a0v = *(const float4*)&angp[0];
        float4 a1v = *(const float4*)&angp[4];
        float4 a2v = *(const float4*)&angp[8];
        float4 a3v = *(const float4*)&angp[12];
        float aw[4] = {a0v.x + a1v.x + a2v.x + a3v.x + dbg[0],
                       a0v.y + a1v.y + a2v.y + a3v.y + dbg[1],
                       a0v.z + a1v.z + a2v.z + a3v.z + dbg[2],
                       a0v.w + a1v.w + a2v.w + a3v.w + dbg[3]};
        int l = t & 15;
        float re = (l == 0) ? 1.f : 0.f;
        float im = 0.f;
        #pragma unroll
        for (int w = 0; w < 4; ++w) {        // initial RY(angle * pi)
            float th = aw[w] * (PI_F * 0.5f);
            float c = cosf(th), s = sinf(th);
            gate1(re, im, l, w, C2{c, 0.f}, C2{-s, 0.f}, C2{s, 0.f}, C2{c, 0.f});
        }
        #pragma unroll
        for (int layer = 0; layer < 2; ++layer) {
            #pragma unroll
            for (int q = 0; q < 4; ++q) {    // precomputed rot gates (uniform)
                const float* gm = wsc + WS_GROT + (layer * 4 + q) * 8;
                gate1(re, im, l, q, C2{gm[0], gm[1]}, C2{gm[2], gm[3]},
                                     C2{gm[4], gm[5]}, C2{gm[6], gm[7]});
            }
            const int pi_[6] = {0, 0, 0, 1, 1, 2};
            const int pj_[6] = {1, 2, 3, 2, 3, 3};
            #pragma unroll
            for (int k = 0; k < 6; ++k) {    // CNOT(i->j) then RZ on j
                int i = pi_[k], j = pj_[k];
                const float* em = wsc + WS_GENT + (layer * 6 + k) * 2;
                float ce = em[0], se = em[1];
                int maskj = 1 << (3 - j);
                float pre = __shfl_xor(re, maskj, 64);
                float pim = __shfl_xor(im, maskj, 64);
                bool bi = ((l >> (3 - i)) & 1) != 0;
                re = bi ? pre : re;
                im = bi ? pim : im;
                bool bj = (l & maskj) != 0;
                C2 ph{ce, bj ? se : -se};
                C2 r = cmul(C2{re, im}, ph);
                re = r.x; im = r.y;
            }
        }
        float pr = re * re + im * im;
        float z0 = ((l >> 3) & 1) ? -pr : pr;
        float z1 = ((l >> 2) & 1) ? -pr : pr;
        float z2 = ((l >> 1) & 1) ? -pr : pr;
        float z3 = (l & 1)        ? -pr : pr;
        #pragma unroll
        for (int m = 1; m <= 8; m <<= 1) {
            z0 += __shfl_xor(z0, m, 64);
            z1 += __shfl_xor(z1, m, 64);
            z2 += __shfl_xor(z2, m, 64);
            z3 += __shfl_xor(z3, m, 64);
        }
        // every lane now holds z0..z3 (identical across the 4 16-lane groups)
        if (t < 10) {
            float4 pw4 = *(const float4*)(pwg + t * 4);
            float o = pbg[t];
            o = fmaf(z0, pw4.x, o); o = fmaf(z1, pw4.y, o);
            o = fmaf(z2, pw4.z, o); o = fmaf(z3, pw4.w, o);
            out[(size_t)b * 10 + t] = o;
        }
    }
}

extern "C" void kernel_launch(void* const* d_in, const int* in_sizes, int n_in,
                              void* d_out, int out_size, void* d_ws, size_t ws_size,
                              hipStream_t stream) {
    const float* x  = (const float*)d_in[0];
    const float* w1 = (const float*)d_in[1];
    const float* b1 = (const float*)d_in[2];
    const float* w2 = (const float*)d_in[3];
    const float* b2 = (const float*)d_in[4];
    const float* dw = (const float*)d_in[5];
    const float* db = (const float*)d_in[6];
    const float* qp = (const float*)d_in[7];
    const float* pw = (const float*)d_in[8];
    const float* pb = (const float*)d_in[9];
    float* out = (float*)d_out;
    float* ws  = (float*)d_ws;
    int B = in_sizes[0] / 784;   // 4096

    qnn_prep<<<1, 256, 0, stream>>>(w1, w2, dw, qp, ws);
    qnn_fused<<<B, 256, 0, stream>>>(x, b1, b2, db, ws, pw, pb, out);
}